// Round 14
// baseline (152.327 us; speedup 1.0000x reference)
//
#include <hip/hip_runtime.h>

#define F_IN 128
#define HID 64
#define C_OUT 40

#define RB_SHIFT 6              // 64 nodes per bucket
#define RB 64
#define CAP 1664                // max (padded) edges per bucket; multiple of 4
#define NBMAX 2048
#define FILL_CHUNK 8192         // edges per block in bsort
#define FILL_THREADS 512
#define AGG_BLOCKS 2048

#define MKBEG(node, b) (((node) >> RB_SHIFT) * CAP + (int)((b) >> 11))

typedef unsigned short ushort_t;
typedef unsigned int uint_t;
typedef __attribute__((ext_vector_type(8))) short bf16x8;
typedef __attribute__((ext_vector_type(4))) float f32x4;

__device__ __forceinline__ ushort_t f2bf(float f) {   // RNE bf16 (manual)
    uint_t u = __float_as_uint(f);
    return (ushort_t)((u + 0x7FFF + ((u >> 16) & 1)) >> 16);
}
__device__ __forceinline__ uint_t cvtpk(float lo, float hi) {  // HW RNE pack
    uint_t r;
    asm("v_cvt_pk_bf16_f32 %0, %1, %2" : "=v"(r) : "v"(lo), "v"(hi));
    return r;
}
__device__ __forceinline__ float bf_lo(uint_t u) { return __uint_as_float(u << 16); }
__device__ __forceinline__ float bf_hi(uint_t u) { return __uint_as_float(u & 0xFFFF0000u); }
__device__ __forceinline__ bf16x8 u4_to_bf(uint4 u) {
    union { uint4 a; bf16x8 b; } cv; cv.a = u; return cv.b;
}

#define ACC8(u) { a[0] += bf_lo(u.x); a[1] += bf_hi(u.x); a[2] += bf_lo(u.y); a[3] += bf_hi(u.y); \
                  a[4] += bf_lo(u.z); a[5] += bf_hi(u.z); a[6] += bf_lo(u.w); a[7] += bf_hi(u.w); }

// ---- per-chunk bucket sort into PRIVATE region; offsets to hist (no global atomics) ----
__global__ __launch_bounds__(FILL_THREADS) void bsort_kernel(
    const int* __restrict__ src, const int* __restrict__ dst, int E,
    int* __restrict__ hist, int* __restrict__ bm, int NB)
{
    __shared__ int lcnt[NBMAX];
    __shared__ int loff[NBMAX];
    __shared__ int wsum[8];
    int t = threadIdx.x;
    for (int i = t; i < NBMAX; i += FILL_THREADS) lcnt[i] = 0;
    __syncthreads();
    int base = blockIdx.x * FILL_CHUNK;
    int nE = min(E - base, FILL_CHUNK);
    #pragma unroll
    for (int k = 0; k < FILL_CHUNK / FILL_THREADS; ++k) {
        int e = k * FILL_THREADS + t;
        if (e < nE) atomicAdd(&lcnt[dst[base + e] >> RB_SHIFT], 1);
    }
    __syncthreads();
    {
        int v[4]; int tsum = 0;
        #pragma unroll
        for (int i = 0; i < 4; ++i) { v[i] = lcnt[t * 4 + i]; tsum += v[i]; }
        int lane = t & 63, wid = t >> 6;
        int incl = tsum;
        #pragma unroll
        for (int off = 1; off < 64; off <<= 1) {
            int u = __shfl_up(incl, off);
            if (lane >= off) incl += u;
        }
        if (lane == 63) wsum[wid] = incl;
        __syncthreads();
        if (t < 8) {
            int wv = wsum[t];
            int wincl = wv;
            #pragma unroll
            for (int off = 1; off < 8; off <<= 1) {
                int u = __shfl_up(wincl, off);
                if (t >= off) wincl += u;
            }
            wsum[t] = wincl - wv;
        }
        __syncthreads();
        int run = wsum[wid] + incl - tsum;
        #pragma unroll
        for (int i = 0; i < 4; ++i) { loff[t * 4 + i] = run; run += v[i]; }
    }
    __syncthreads();
    long long hrow = (long long)blockIdx.x * (NB + 1);
    for (int i = t; i < NB; i += FILL_THREADS) hist[hrow + i] = loff[i];
    if (t == 0) hist[hrow + NB] = nE;
    __syncthreads();
    #pragma unroll
    for (int k = 0; k < FILL_CHUNK / FILL_THREADS; ++k) {
        int e = k * FILL_THREADS + t;
        if (e < nE) {
            int d = dst[base + e], s = src[base + e];
            int b = d >> RB_SHIFT;
            int pos = atomicAdd(&loff[b], 1);
            bm[base + pos] = (s << RB_SHIFT) | (d & (RB - 1));
        }
    }
}

// ---- gather bucket's runs; counting sort with 16B-ALIGNED per-node segments ----
__global__ __launch_bounds__(256) void csr_gather_kernel(
    const int* __restrict__ hist, const int* __restrict__ bm, int K,
    int* __restrict__ csr, uint_t* __restrict__ bd,
    float* __restrict__ dinv, int N, int NB)
{
    __shared__ int staging[CAP];
    __shared__ int histo[RB];
    __shared__ int cursor[RB];
    __shared__ int waux[8];
    int t = threadIdx.x;
    int b = blockIdx.x;
    int len = 0, st = 0;
    if (t < K) {
        long long hrow = (long long)t * (NB + 1);
        st = hist[hrow + b];
        len = hist[hrow + b + 1] - st;
    }
    int lane = t & 63, wid = t >> 6;
    int incl = len;
    #pragma unroll
    for (int off = 1; off < 64; off <<= 1) {
        int u = __shfl_up(incl, off);
        if (lane >= off) incl += u;
    }
    if (lane == 63) waux[wid] = incl;
    if (t < RB) histo[t] = 0;
    __syncthreads();
    if (t < 4) {
        int w = waux[t];
        int wincl = w;
        #pragma unroll
        for (int off = 1; off < 4; off <<= 1) {
            int u = __shfl_up(wincl, off);
            if (t >= off) wincl += u;
        }
        waux[t] = wincl - w;
        if (t == 3) waux[4] = wincl;
    }
    __syncthreads();
    int bpos = waux[wid] + incl - len;
    int cnt = waux[4];
    if (cnt > CAP - 192) cnt = CAP - 192;   // padded total must fit CAP
    if (t < K && len > 0) {
        int gbase = t * FILL_CHUNK + st;
        for (int i = 0; i < len; ++i) {
            int p = bpos + i;
            if (p < CAP - 192) staging[p] = bm[gbase + i];
        }
    }
    __syncthreads();
    for (int i = t; i < cnt; i += 256) atomicAdd(&histo[staging[i] & (RB - 1)], 1);
    __syncthreads();
    if (t < RB) {
        int v = histo[t];
        int pv = (v + 3) & ~3;             // pad each segment to x4 (16B)
        int nincl = pv;
        #pragma unroll
        for (int off = 1; off < 64; off <<= 1) {
            int u = __shfl_up(nincl, off);
            if (t >= off) nincl += u;
        }
        int excl = nincl - pv;             // multiple of 4
        cursor[t] = excl;
        int node = b * RB + t;
        if (node < N) {
            bd[node] = ((uint_t)excl << 11) | (uint_t)v;
            dinv[node] = rsqrtf((float)(v + 1));   // +1 self-loop
        }
    }
    __syncthreads();
    int cbase = b * CAP;
    for (int i = t; i < cnt; i += 256) {
        int e = staging[i];
        int n = e & (RB - 1);
        int r = atomicAdd(&cursor[n], 1);
        csr[cbase + r] = e >> RB_SHIFT;
    }
}

// ---- W1 & W2 -> fragment-linear bf16 ----
__global__ void wconv_kernel(const float* __restrict__ W1, const float* __restrict__ W2,
                             ushort_t* __restrict__ wb1, ushort_t* __restrict__ wb2)
{
    int tid = blockIdx.x * 256 + threadIdx.x;
    if (tid < 8192) {
        int j = tid & 7, l = (tid >> 3) & 63, ks = (tid >> 9) & 3, ct = tid >> 11;
        int c = ct * 16 + (l & 15);
        int k = ks * 32 + (l >> 4) * 8 + j;
        wb1[tid] = f2bf(W1[k * HID + c]);
    } else if (tid < 8192 + 3072) {
        int s = tid - 8192;
        int j = s & 7, l = (s >> 3) & 63, ks = (s >> 9) & 1, ct = s >> 10;
        int c = ct * 16 + (l & 15);
        int k = ks * 32 + (l >> 4) * 8 + j;
        wb2[s] = (c < C_OUT) ? f2bf(W2[k * C_OUT + c]) : (ushort_t)0;
    }
}

// ---- GEMM1 (MFMA): y[N,32 uints] = bf16pack((x @ W1) * dinv[row]) ----
__global__ __launch_bounds__(256) void gemm1_mfma(
    const float* __restrict__ x, const uint_t* __restrict__ Wb,
    const float* __restrict__ dinv, uint_t* __restrict__ y, int N)
{
    __shared__ uint_t ldsW[4096];   // 16 KB
    int t = threadIdx.x;
    {
        const uint4* s4 = (const uint4*)Wb;
        uint4* d4 = (uint4*)ldsW;
        for (int i = t; i < 1024; i += 256) d4[i] = s4[i];
    }
    __syncthreads();
    int wid = t >> 6, lane = t & 63;
    int m = lane & 15, kb = lane >> 4;
    int wr = blockIdx.x * 128 + wid * 32;
    int ra0 = min(wr + m, N - 1);
    int ra1 = min(wr + 16 + m, N - 1);
    f32x4 acc[2][4] = {};
    #pragma unroll
    for (int ks = 0; ks < 4; ++ks) {
        const float* p0 = &x[(size_t)ra0 * F_IN + ks * 32 + kb * 8];
        const float* p1 = &x[(size_t)ra1 * F_IN + ks * 32 + kb * 8];
        float4 a0 = *(const float4*)p0, a1 = *(const float4*)(p0 + 4);
        float4 c0 = *(const float4*)p1, c1 = *(const float4*)(p1 + 4);
        uint4 ua = make_uint4(cvtpk(a0.x, a0.y), cvtpk(a0.z, a0.w),
                              cvtpk(a1.x, a1.y), cvtpk(a1.z, a1.w));
        uint4 ub = make_uint4(cvtpk(c0.x, c0.y), cvtpk(c0.z, c0.w),
                              cvtpk(c1.x, c1.y), cvtpk(c1.z, c1.w));
        bf16x8 fa0 = u4_to_bf(ua), fa1 = u4_to_bf(ub);
        #pragma unroll
        for (int ct = 0; ct < 4; ++ct) {
            uint4 wu = *(uint4*)&ldsW[((ct * 4 + ks) * 64 + lane) * 4];
            bf16x8 fb = u4_to_bf(wu);
            acc[0][ct] = __builtin_amdgcn_mfma_f32_16x16x32_bf16(fa0, fb, acc[0][ct], 0, 0, 0);
            acc[1][ct] = __builtin_amdgcn_mfma_f32_16x16x32_bf16(fa1, fb, acc[1][ct], 0, 0, 0);
        }
    }
    int rq = lane >> 4;
    #pragma unroll
    for (int rt = 0; rt < 2; ++rt) {
        float dv[4]; int rows[4];
        #pragma unroll
        for (int j = 0; j < 4; ++j) {
            int r = wr + rt * 16 + rq * 4 + j;
            rows[j] = r;
            dv[j] = dinv[min(r, N - 1)];
        }
        #pragma unroll
        for (int ct = 0; ct < 4; ++ct) {
            #pragma unroll
            for (int j = 0; j < 4; ++j) {
                float v = acc[rt][ct][j] * dv[j];
                float pv = __shfl_xor(v, 1);
                if (!(lane & 1) && rows[j] < N) {
                    y[(size_t)rows[j] * 32 + ct * 8 + (m >> 1)] = cvtpk(v, pv);
                }
            }
        }
    }
}

// ---- agg1: 32-edge uint4-index prefetch pipeline; h(bf16) = relu((sum+self)*dinv+b) ----
__global__ __launch_bounds__(256) void agg1_kernel(
    const int* __restrict__ csr, const uint_t* __restrict__ bd,
    const uint_t* __restrict__ y, const float* __restrict__ dinv,
    const float* __restrict__ bias, uint_t* __restrict__ h, int N, int stride)
{
    int w = blockIdx.x * 4 + (threadIdx.x >> 6);
    if (w >= N) return;
    int lane = threadIdx.x & 63;
    int o = lane >> 3, c = lane & 7;
    int slot = 4 * o;                      // edge slots slot..slot+3

    int n1 = w + stride, n2 = w + 2 * stride;
    uint_t bd0 = bd[w];
    uint_t bd1 = (n1 < N) ? bd[n1] : 0u;
    uint4 idx0 = *(const uint4*)&csr[MKBEG(w, bd0) + slot];

    for (int node = w; node < N; ) {
        uint_t bd2 = (n2 < N) ? bd[n2] : 0u;            // prefetch bd +2
        uint4 idx1 = make_uint4(0u, 0u, 0u, 0u);        // prefetch indices +1
        if (n1 < N) idx1 = *(const uint4*)&csr[MKBEG(n1, bd1) + slot];
        int deg0 = (int)(bd0 & 2047u);
        float a[8] = {};
        if (o == 0) { uint4 u = *(const uint4*)&y[(size_t)node * 32 + c * 4]; ACC8(u); }
        if (slot + 0 < deg0) { uint4 u = *(const uint4*)&y[(size_t)idx0.x * 32 + c * 4]; ACC8(u); }
        if (slot + 1 < deg0) { uint4 u = *(const uint4*)&y[(size_t)idx0.y * 32 + c * 4]; ACC8(u); }
        if (slot + 2 < deg0) { uint4 u = *(const uint4*)&y[(size_t)idx0.z * 32 + c * 4]; ACC8(u); }
        if (slot + 3 < deg0) { uint4 u = *(const uint4*)&y[(size_t)idx0.w * 32 + c * 4]; ACC8(u); }
        if (deg0 > 32) {                                // rare (P ~ 1e-4)
            int beg0 = MKBEG(node, bd0);
            for (int j = 32; j < deg0; j += 32) {
                int s = j + slot;
                #pragma unroll
                for (int k = 0; k < 4; ++k) {
                    if (s + k < deg0) {
                        int e = csr[beg0 + s + k];
                        uint4 u = *(const uint4*)&y[(size_t)e * 32 + c * 4]; ACC8(u);
                    }
                }
            }
        }
        #pragma unroll
        for (int k = 0; k < 8; ++k) {
            a[k] += __shfl_xor(a[k], 8);
            a[k] += __shfl_xor(a[k], 16);
            a[k] += __shfl_xor(a[k], 32);
        }
        if (o == 0) {
            float di = dinv[node];
            float4 b0 = *(const float4*)&bias[c * 8];
            float4 b1 = *(const float4*)&bias[c * 8 + 4];
            float o0 = fmaxf(a[0] * di + b0.x, 0.f);
            float o1 = fmaxf(a[1] * di + b0.y, 0.f);
            float o2 = fmaxf(a[2] * di + b0.z, 0.f);
            float o3 = fmaxf(a[3] * di + b0.w, 0.f);
            float o4 = fmaxf(a[4] * di + b1.x, 0.f);
            float o5 = fmaxf(a[5] * di + b1.y, 0.f);
            float o6 = fmaxf(a[6] * di + b1.z, 0.f);
            float o7 = fmaxf(a[7] * di + b1.w, 0.f);
            uint4 r = make_uint4(cvtpk(o0, o1), cvtpk(o2, o3), cvtpk(o4, o5), cvtpk(o6, o7));
            *(uint4*)&h[(size_t)node * 32 + c * 4] = r;
        }
        node = n1; n1 = n2; n2 += stride;
        bd0 = bd1; bd1 = bd2; idx0 = idx1;
    }
}

// ---- GEMM2 (MFMA): y2[N,32 uints, cols 0..39] = bf16pack((h @ W2) * dinv[row]) ----
__global__ __launch_bounds__(256) void gemm2_mfma(
    const uint_t* __restrict__ h, const uint_t* __restrict__ Wb,
    const float* __restrict__ dinv, uint_t* __restrict__ y, int N)
{
    __shared__ uint_t ldsW[1536];   // 6 KB
    int t = threadIdx.x;
    {
        const uint4* s4 = (const uint4*)Wb;
        uint4* d4 = (uint4*)ldsW;
        for (int i = t; i < 384; i += 256) d4[i] = s4[i];
    }
    __syncthreads();
    int wid = t >> 6, lane = t & 63;
    int m = lane & 15, kb = lane >> 4;
    int wr = blockIdx.x * 128 + wid * 32;
    int ra0 = min(wr + m, N - 1);
    int ra1 = min(wr + 16 + m, N - 1);
    f32x4 acc[2][3] = {};
    #pragma unroll
    for (int ks = 0; ks < 2; ++ks) {
        uint4 ua = *(const uint4*)&h[(size_t)ra0 * 32 + ks * 16 + kb * 4];
        uint4 ub = *(const uint4*)&h[(size_t)ra1 * 32 + ks * 16 + kb * 4];
        bf16x8 fa0 = u4_to_bf(ua), fa1 = u4_to_bf(ub);
        #pragma unroll
        for (int ct = 0; ct < 3; ++ct) {
            uint4 wu = *(uint4*)&ldsW[((ct * 2 + ks) * 64 + lane) * 4];
            bf16x8 fb = u4_to_bf(wu);
            acc[0][ct] = __builtin_amdgcn_mfma_f32_16x16x32_bf16(fa0, fb, acc[0][ct], 0, 0, 0);
            acc[1][ct] = __builtin_amdgcn_mfma_f32_16x16x32_bf16(fa1, fb, acc[1][ct], 0, 0, 0);
        }
    }
    int rq = lane >> 4;
    #pragma unroll
    for (int rt = 0; rt < 2; ++rt) {
        float dv[4]; int rows[4];
        #pragma unroll
        for (int j = 0; j < 4; ++j) {
            int r = wr + rt * 16 + rq * 4 + j;
            rows[j] = r;
            dv[j] = dinv[min(r, N - 1)];
        }
        #pragma unroll
        for (int ct = 0; ct < 3; ++ct) {
            #pragma unroll
            for (int j = 0; j < 4; ++j) {
                float v = acc[rt][ct][j] * dv[j];
                float pv = __shfl_xor(v, 1);
                bool colok = (ct < 2) || (m < 8);   // col = ct*16+m < 40
                if (!(lane & 1) && colok && rows[j] < N) {
                    y[(size_t)rows[j] * 32 + ct * 8 + (m >> 1)] = cvtpk(v, pv);
                }
            }
        }
    }
}

// ---- agg2: 32-edge uint4-index prefetch pipeline (5 active uint4 lanes) ----
__global__ __launch_bounds__(256) void agg2_kernel(
    const int* __restrict__ csr, const uint_t* __restrict__ bd,
    const uint_t* __restrict__ y, const float* __restrict__ dinv,
    const float* __restrict__ bias, float* __restrict__ out, int N, int stride)
{
    int w = blockIdx.x * 4 + (threadIdx.x >> 6);
    if (w >= N) return;
    int lane = threadIdx.x & 63;
    int o = lane >> 3, c = lane & 7;
    int slot = 4 * o;
    bool act = (c < 5);

    int n1 = w + stride, n2 = w + 2 * stride;
    uint_t bd0 = bd[w];
    uint_t bd1 = (n1 < N) ? bd[n1] : 0u;
    uint4 idx0 = *(const uint4*)&csr[MKBEG(w, bd0) + slot];

    for (int node = w; node < N; ) {
        uint_t bd2 = (n2 < N) ? bd[n2] : 0u;
        uint4 idx1 = make_uint4(0u, 0u, 0u, 0u);
        if (n1 < N) idx1 = *(const uint4*)&csr[MKBEG(n1, bd1) + slot];
        int deg0 = (int)(bd0 & 2047u);
        float a[8] = {};
        if (o == 0 && act) { uint4 u = *(const uint4*)&y[(size_t)node * 32 + c * 4]; ACC8(u); }
        if (act && slot + 0 < deg0) { uint4 u = *(const uint4*)&y[(size_t)idx0.x * 32 + c * 4]; ACC8(u); }
        if (act && slot + 1 < deg0) { uint4 u = *(const uint4*)&y[(size_t)idx0.y * 32 + c * 4]; ACC8(u); }
        if (act && slot + 2 < deg0) { uint4 u = *(const uint4*)&y[(size_t)idx0.z * 32 + c * 4]; ACC8(u); }
        if (act && slot + 3 < deg0) { uint4 u = *(const uint4*)&y[(size_t)idx0.w * 32 + c * 4]; ACC8(u); }
        if (deg0 > 32) {
            int beg0 = MKBEG(node, bd0);
            for (int j = 32; j < deg0; j += 32) {
                int s = j + slot;
                #pragma unroll
                for (int k = 0; k < 4; ++k) {
                    if (act && s + k < deg0) {
                        int e = csr[beg0 + s + k];
                        uint4 u = *(const uint4*)&y[(size_t)e * 32 + c * 4]; ACC8(u);
                    }
                }
            }
        }
        #pragma unroll
        for (int k = 0; k < 8; ++k) {
            a[k] += __shfl_xor(a[k], 8);
            a[k] += __shfl_xor(a[k], 16);
            a[k] += __shfl_xor(a[k], 32);
        }
        if (o == 0 && act) {
            float di = dinv[node];
            float4 b0 = *(const float4*)&bias[c * 8];
            float4 b1 = *(const float4*)&bias[c * 8 + 4];
            float4 r0, r1;
            r0.x = a[0] * di + b0.x;
            r0.y = a[1] * di + b0.y;
            r0.z = a[2] * di + b0.z;
            r0.w = a[3] * di + b0.w;
            r1.x = a[4] * di + b1.x;
            r1.y = a[5] * di + b1.y;
            r1.z = a[6] * di + b1.z;
            r1.w = a[7] * di + b1.w;
            *(float4*)&out[(size_t)node * C_OUT + c * 8] = r0;
            *(float4*)&out[(size_t)node * C_OUT + c * 8 + 4] = r1;
        }
        node = n1; n1 = n2; n2 += stride;
        bd0 = bd1; bd1 = bd2; idx0 = idx1;
    }
}

extern "C" void kernel_launch(void* const* d_in, const int* in_sizes, int n_in,
                              void* d_out, int out_size, void* d_ws, size_t ws_size,
                              hipStream_t stream)
{
    const float* x  = (const float*)d_in[0];
    const int*   ei = (const int*)d_in[1];
    const float* W1 = (const float*)d_in[2];
    const float* b1 = (const float*)d_in[3];
    const float* W2 = (const float*)d_in[4];
    const float* b2 = (const float*)d_in[5];
    float* out = (float*)d_out;

    int N = in_sizes[0] / F_IN;
    int E = in_sizes[1] / 2;
    const int* src = ei;
    const int* dst = ei + E;
    int NB = (N + RB - 1) / RB;
    int K = (E + FILL_CHUNK - 1) / FILL_CHUNK;
    int NBLK = (N + 127) / 128;
    int aggStride = AGG_BLOCKS * 4;

    char* ws = (char*)d_ws;
    uint_t* y1b    = (uint_t*)ws;  ws += (size_t)N * 32 * 4;   // bf16x2 xW1*dinv
    uint_t* y2b    = (uint_t*)ws;  ws += (size_t)N * 32 * 4;   // bf16x2 hW2*dinv
    uint_t* h1p    = (uint_t*)ws;  ws += (size_t)N * 32 * 4;   // bf16x2 relu'd h
    float* dinv    = (float*)ws;   ws += (size_t)N * 4;
    uint_t* bd     = (uint_t*)ws;  ws += (size_t)N * 4;        // packed (excl<<11)|deg
    int*   hist    = (int*)ws;     ws += (size_t)K * (NB + 1) * 4;
    int*   bm      = (int*)ws;     ws += (size_t)K * FILL_CHUNK * 4;
    int*   csr     = (int*)ws;     ws += ((size_t)NB * CAP + 128) * 4;  // +tail slack for uint4 over-read
    ushort_t* wb1  = (ushort_t*)ws; ws += 8192 * 2;            // W1 frag-linear bf16
    ushort_t* wb2  = (ushort_t*)ws; ws += 3072 * 2;            // W2 frag-linear bf16 (48-pad)

    wconv_kernel<<<44, 256, 0, stream>>>(W1, W2, wb1, wb2);

    bsort_kernel<<<K, FILL_THREADS, 0, stream>>>(src, dst, E, hist, bm, NB);
    csr_gather_kernel<<<NB, 256, 0, stream>>>(hist, bm, K, csr, bd, dinv, N, NB);

    // layer 1
    gemm1_mfma<<<NBLK, 256, 0, stream>>>(x, (const uint_t*)wb1, dinv, y1b, N);
    agg1_kernel<<<AGG_BLOCKS, 256, 0, stream>>>(csr, bd, y1b, dinv, b1, h1p, N, aggStride);

    // layer 2
    gemm2_mfma<<<NBLK, 256, 0, stream>>>(h1p, (const uint_t*)wb2, dinv, y2b, N);
    agg2_kernel<<<AGG_BLOCKS, 256, 0, stream>>>(csr, bd, y2b, dinv, b2, out, N, aggStride);
}

// Round 15
// 151.446 us; speedup vs baseline: 1.0058x; 1.0058x over previous
//
#include <hip/hip_runtime.h>

#define F_IN 128
#define HID 64
#define C_OUT 40

#define RB_SHIFT 6              // 64 nodes per bucket
#define RB 64
#define CAP 1408                // max edges per bucket (mean 1024, +12 sigma)
#define NBMAX 2048
#define FILL_CHUNK 8192         // edges per block in bsort
#define FILL_THREADS 512
#define AGG_BLOCKS 2048
#define Y2W 20                  // packed y2 row width in uints (80 B)

#define MKBEG(node, b) (((node) >> RB_SHIFT) * CAP + (int)((b) >> 11))

typedef unsigned short ushort_t;
typedef unsigned int uint_t;
typedef __attribute__((ext_vector_type(8))) short bf16x8;
typedef __attribute__((ext_vector_type(4))) float f32x4;
typedef __attribute__((ext_vector_type(2))) float f32x2;

__device__ __forceinline__ ushort_t f2bf(float f) {   // RNE bf16 (manual)
    uint_t u = __float_as_uint(f);
    return (ushort_t)((u + 0x7FFF + ((u >> 16) & 1)) >> 16);
}
__device__ __forceinline__ uint_t cvtpk(float lo, float hi) {  // HW RNE pack
    uint_t r;
    asm("v_cvt_pk_bf16_f32 %0, %1, %2" : "=v"(r) : "v"(lo), "v"(hi));
    return r;
}
__device__ __forceinline__ float bf_lo(uint_t u) { return __uint_as_float(u << 16); }
__device__ __forceinline__ float bf_hi(uint_t u) { return __uint_as_float(u & 0xFFFF0000u); }
__device__ __forceinline__ bf16x8 u4_to_bf(uint4 u) {
    union { uint4 a; bf16x8 b; } cv; cv.a = u; return cv.b;
}

// packed accumulate: 4x f32x2 += unpacked pairs (compiler emits v_pk_add_f32)
#define ACCP(u) { a[0] += (f32x2){bf_lo(u.x), bf_hi(u.x)}; \
                  a[1] += (f32x2){bf_lo(u.y), bf_hi(u.y)}; \
                  a[2] += (f32x2){bf_lo(u.z), bf_hi(u.z)}; \
                  a[3] += (f32x2){bf_lo(u.w), bf_hi(u.w)}; }

// ---- per-chunk bucket sort into PRIVATE region; offsets to hist (no global atomics) ----
__global__ __launch_bounds__(FILL_THREADS) void bsort_kernel(
    const int* __restrict__ src, const int* __restrict__ dst, int E,
    int* __restrict__ hist, int* __restrict__ bm, int NB)
{
    __shared__ int lcnt[NBMAX];
    __shared__ int loff[NBMAX];
    __shared__ int wsum[8];
    int t = threadIdx.x;
    for (int i = t; i < NBMAX; i += FILL_THREADS) lcnt[i] = 0;
    __syncthreads();
    int base = blockIdx.x * FILL_CHUNK;
    int nE = min(E - base, FILL_CHUNK);
    #pragma unroll
    for (int k = 0; k < FILL_CHUNK / FILL_THREADS; ++k) {
        int e = k * FILL_THREADS + t;
        if (e < nE) atomicAdd(&lcnt[dst[base + e] >> RB_SHIFT], 1);
    }
    __syncthreads();
    {
        int v[4]; int tsum = 0;
        #pragma unroll
        for (int i = 0; i < 4; ++i) { v[i] = lcnt[t * 4 + i]; tsum += v[i]; }
        int lane = t & 63, wid = t >> 6;
        int incl = tsum;
        #pragma unroll
        for (int off = 1; off < 64; off <<= 1) {
            int u = __shfl_up(incl, off);
            if (lane >= off) incl += u;
        }
        if (lane == 63) wsum[wid] = incl;
        __syncthreads();
        if (t < 8) {
            int wv = wsum[t];
            int wincl = wv;
            #pragma unroll
            for (int off = 1; off < 8; off <<= 1) {
                int u = __shfl_up(wincl, off);
                if (t >= off) wincl += u;
            }
            wsum[t] = wincl - wv;
        }
        __syncthreads();
        int run = wsum[wid] + incl - tsum;
        #pragma unroll
        for (int i = 0; i < 4; ++i) { loff[t * 4 + i] = run; run += v[i]; }
    }
    __syncthreads();
    long long hrow = (long long)blockIdx.x * (NB + 1);
    for (int i = t; i < NB; i += FILL_THREADS) hist[hrow + i] = loff[i];
    if (t == 0) hist[hrow + NB] = nE;
    __syncthreads();
    #pragma unroll
    for (int k = 0; k < FILL_CHUNK / FILL_THREADS; ++k) {
        int e = k * FILL_THREADS + t;
        if (e < nE) {
            int d = dst[base + e], s = src[base + e];
            int b = d >> RB_SHIFT;
            int pos = atomicAdd(&loff[b], 1);
            bm[base + pos] = (s << RB_SHIFT) | (d & (RB - 1));
        }
    }
}

// ---- gather bucket's runs; per-node counting sort -> CSR + packed (excl,deg) + dinv ----
__global__ __launch_bounds__(256) void csr_gather_kernel(
    const int* __restrict__ hist, const int* __restrict__ bm, int K,
    int* __restrict__ csr, uint_t* __restrict__ bd,
    float* __restrict__ dinv, int N, int NB)
{
    __shared__ int staging[CAP];
    __shared__ int histo[RB];
    __shared__ int cursor[RB];
    __shared__ int waux[8];
    int t = threadIdx.x;
    int b = blockIdx.x;
    int len = 0, st = 0;
    if (t < K) {
        long long hrow = (long long)t * (NB + 1);
        st = hist[hrow + b];
        len = hist[hrow + b + 1] - st;
    }
    int lane = t & 63, wid = t >> 6;
    int incl = len;
    #pragma unroll
    for (int off = 1; off < 64; off <<= 1) {
        int u = __shfl_up(incl, off);
        if (lane >= off) incl += u;
    }
    if (lane == 63) waux[wid] = incl;
    if (t < RB) histo[t] = 0;
    __syncthreads();
    if (t < 4) {
        int w = waux[t];
        int wincl = w;
        #pragma unroll
        for (int off = 1; off < 4; off <<= 1) {
            int u = __shfl_up(wincl, off);
            if (t >= off) wincl += u;
        }
        waux[t] = wincl - w;
        if (t == 3) waux[4] = wincl;
    }
    __syncthreads();
    int bpos = waux[wid] + incl - len;
    int cnt = waux[4];
    if (cnt > CAP) cnt = CAP;
    if (t < K && len > 0) {
        int gbase = t * FILL_CHUNK + st;
        for (int i = 0; i < len; ++i) {
            int p = bpos + i;
            if (p < CAP) staging[p] = bm[gbase + i];
        }
    }
    __syncthreads();
    for (int i = t; i < cnt; i += 256) atomicAdd(&histo[staging[i] & (RB - 1)], 1);
    __syncthreads();
    if (t < RB) {
        int v = histo[t];
        int nincl = v;
        #pragma unroll
        for (int off = 1; off < 64; off <<= 1) {
            int u = __shfl_up(nincl, off);
            if (t >= off) nincl += u;
        }
        int excl = nincl - v;
        cursor[t] = excl;
        int node = b * RB + t;
        if (node < N) {
            bd[node] = ((uint_t)excl << 11) | (uint_t)v;
            dinv[node] = rsqrtf((float)(v + 1));   // +1 self-loop
        }
    }
    __syncthreads();
    int cbase = b * CAP;
    for (int i = t; i < cnt; i += 256) {
        int e = staging[i];
        int n = e & (RB - 1);
        int r = atomicAdd(&cursor[n], 1);
        csr[cbase + r] = e >> RB_SHIFT;
    }
}

// ---- W1 & W2 -> fragment-linear bf16 ----
__global__ void wconv_kernel(const float* __restrict__ W1, const float* __restrict__ W2,
                             ushort_t* __restrict__ wb1, ushort_t* __restrict__ wb2)
{
    int tid = blockIdx.x * 256 + threadIdx.x;
    if (tid < 8192) {
        int j = tid & 7, l = (tid >> 3) & 63, ks = (tid >> 9) & 3, ct = tid >> 11;
        int c = ct * 16 + (l & 15);
        int k = ks * 32 + (l >> 4) * 8 + j;
        wb1[tid] = f2bf(W1[k * HID + c]);
    } else if (tid < 8192 + 3072) {
        int s = tid - 8192;
        int j = s & 7, l = (s >> 3) & 63, ks = (s >> 9) & 1, ct = s >> 10;
        int c = ct * 16 + (l & 15);
        int k = ks * 32 + (l >> 4) * 8 + j;
        wb2[s] = (c < C_OUT) ? f2bf(W2[k * C_OUT + c]) : (ushort_t)0;
    }
}

// ---- GEMM1 (MFMA): y[N,32 uints] = bf16pack((x @ W1) * dinv[row]) ----
__global__ __launch_bounds__(256) void gemm1_mfma(
    const float* __restrict__ x, const uint_t* __restrict__ Wb,
    const float* __restrict__ dinv, uint_t* __restrict__ y, int N)
{
    __shared__ uint_t ldsW[4096];   // 16 KB
    int t = threadIdx.x;
    {
        const uint4* s4 = (const uint4*)Wb;
        uint4* d4 = (uint4*)ldsW;
        for (int i = t; i < 1024; i += 256) d4[i] = s4[i];
    }
    __syncthreads();
    int wid = t >> 6, lane = t & 63;
    int m = lane & 15, kb = lane >> 4;
    int wr = blockIdx.x * 128 + wid * 32;
    int ra0 = min(wr + m, N - 1);
    int ra1 = min(wr + 16 + m, N - 1);
    f32x4 acc[2][4] = {};
    #pragma unroll
    for (int ks = 0; ks < 4; ++ks) {
        const float* p0 = &x[(size_t)ra0 * F_IN + ks * 32 + kb * 8];
        const float* p1 = &x[(size_t)ra1 * F_IN + ks * 32 + kb * 8];
        float4 a0 = *(const float4*)p0, a1 = *(const float4*)(p0 + 4);
        float4 c0 = *(const float4*)p1, c1 = *(const float4*)(p1 + 4);
        uint4 ua = make_uint4(cvtpk(a0.x, a0.y), cvtpk(a0.z, a0.w),
                              cvtpk(a1.x, a1.y), cvtpk(a1.z, a1.w));
        uint4 ub = make_uint4(cvtpk(c0.x, c0.y), cvtpk(c0.z, c0.w),
                              cvtpk(c1.x, c1.y), cvtpk(c1.z, c1.w));
        bf16x8 fa0 = u4_to_bf(ua), fa1 = u4_to_bf(ub);
        #pragma unroll
        for (int ct = 0; ct < 4; ++ct) {
            uint4 wu = *(uint4*)&ldsW[((ct * 4 + ks) * 64 + lane) * 4];
            bf16x8 fb = u4_to_bf(wu);
            acc[0][ct] = __builtin_amdgcn_mfma_f32_16x16x32_bf16(fa0, fb, acc[0][ct], 0, 0, 0);
            acc[1][ct] = __builtin_amdgcn_mfma_f32_16x16x32_bf16(fa1, fb, acc[1][ct], 0, 0, 0);
        }
    }
    int rq = lane >> 4;
    #pragma unroll
    for (int rt = 0; rt < 2; ++rt) {
        float dv[4]; int rows[4];
        #pragma unroll
        for (int j = 0; j < 4; ++j) {
            int r = wr + rt * 16 + rq * 4 + j;
            rows[j] = r;
            dv[j] = dinv[min(r, N - 1)];
        }
        #pragma unroll
        for (int ct = 0; ct < 4; ++ct) {
            #pragma unroll
            for (int j = 0; j < 4; ++j) {
                float v = acc[rt][ct][j] * dv[j];
                float pv = __shfl_xor(v, 1);
                if (!(lane & 1) && rows[j] < N) {
                    y[(size_t)rows[j] * 32 + ct * 8 + (m >> 1)] = cvtpk(v, pv);
                }
            }
        }
    }
}

// ---- agg1: grid-stride, 2-deep pipelined gather; h(bf16) = relu((sum+self)*dinv+b) ----
__global__ __launch_bounds__(256) void agg1_kernel(
    const int* __restrict__ csr, const uint_t* __restrict__ bd,
    const uint_t* __restrict__ y, const float* __restrict__ dinv,
    const float* __restrict__ bias, uint_t* __restrict__ h, int N, int stride)
{
    int w = blockIdx.x * 4 + (threadIdx.x >> 6);
    if (w >= N) return;
    int lane = threadIdx.x & 63;
    int o = lane >> 3, c = lane & 7;

    int n1 = w + stride, n2 = w + 2 * stride;
    uint_t bd0 = bd[w];
    uint_t bd1 = (n1 < N) ? bd[n1] : 0u;
    uint2 idx0;
    {
        int beg0 = MKBEG(w, bd0), end0 = beg0 + (int)(bd0 & 2047u);
        int j0 = beg0 + 2 * o;
        idx0.x = (j0 < end0) ? (uint_t)csr[j0] : 0xFFFFFFFFu;
        idx0.y = (j0 + 1 < end0) ? (uint_t)csr[j0 + 1] : 0xFFFFFFFFu;
    }

    for (int node = w; node < N; ) {
        uint_t bd2 = (n2 < N) ? bd[n2] : 0u;         // prefetch +2
        uint2 idx1;                                   // prefetch +1 indices
        {
            int beg1 = MKBEG(n1, bd1), end1 = beg1 + (int)(bd1 & 2047u);
            int j0 = beg1 + 2 * o;
            idx1.x = (j0 < end1) ? (uint_t)csr[j0] : 0xFFFFFFFFu;
            idx1.y = (j0 + 1 < end1) ? (uint_t)csr[j0 + 1] : 0xFFFFFFFFu;
        }
        f32x2 a[4] = {};
        if (o == 0) {
            uint4 u = *(const uint4*)&y[(size_t)node * 32 + c * 4];
            ACCP(u);
        }
        if (idx0.x != 0xFFFFFFFFu) { uint4 u = *(const uint4*)&y[(size_t)idx0.x * 32 + c * 4]; ACCP(u); }
        if (idx0.y != 0xFFFFFFFFu) { uint4 u = *(const uint4*)&y[(size_t)idx0.y * 32 + c * 4]; ACCP(u); }
        int beg0 = MKBEG(node, bd0), end0 = beg0 + (int)(bd0 & 2047u);
        for (int j = beg0 + 16; j < end0; j += 16) {
            int j0 = j + 2 * o;
            int i0 = (j0 < end0) ? csr[j0] : -1;
            int i1 = (j0 + 1 < end0) ? csr[j0 + 1] : -1;
            if (i0 >= 0) { uint4 u = *(const uint4*)&y[(size_t)i0 * 32 + c * 4]; ACCP(u); }
            if (i1 >= 0) { uint4 u = *(const uint4*)&y[(size_t)i1 * 32 + c * 4]; ACCP(u); }
        }
        #pragma unroll
        for (int k = 0; k < 4; ++k) {
            a[k].x += __shfl_xor(a[k].x, 8);  a[k].y += __shfl_xor(a[k].y, 8);
            a[k].x += __shfl_xor(a[k].x, 16); a[k].y += __shfl_xor(a[k].y, 16);
            a[k].x += __shfl_xor(a[k].x, 32); a[k].y += __shfl_xor(a[k].y, 32);
        }
        if (o == 0) {
            float di = dinv[node];
            float4 b0 = *(const float4*)&bias[c * 8];
            float4 b1 = *(const float4*)&bias[c * 8 + 4];
            float o0 = fmaxf(a[0].x * di + b0.x, 0.f);
            float o1 = fmaxf(a[0].y * di + b0.y, 0.f);
            float o2 = fmaxf(a[1].x * di + b0.z, 0.f);
            float o3 = fmaxf(a[1].y * di + b0.w, 0.f);
            float o4 = fmaxf(a[2].x * di + b1.x, 0.f);
            float o5 = fmaxf(a[2].y * di + b1.y, 0.f);
            float o6 = fmaxf(a[3].x * di + b1.z, 0.f);
            float o7 = fmaxf(a[3].y * di + b1.w, 0.f);
            uint4 r = make_uint4(cvtpk(o0, o1), cvtpk(o2, o3), cvtpk(o4, o5), cvtpk(o6, o7));
            *(uint4*)&h[(size_t)node * 32 + c * 4] = r;
        }
        node = n1; n1 = n2; n2 += stride;
        bd0 = bd1; bd1 = bd2; idx0 = idx1;
    }
}

// ---- GEMM2 (MFMA): y2[N, 20 uints packed] = bf16pack((h @ W2) * dinv[row]) ----
__global__ __launch_bounds__(256) void gemm2_mfma(
    const uint_t* __restrict__ h, const uint_t* __restrict__ Wb,
    const float* __restrict__ dinv, uint_t* __restrict__ y, int N)
{
    __shared__ uint_t ldsW[1536];   // 6 KB
    int t = threadIdx.x;
    {
        const uint4* s4 = (const uint4*)Wb;
        uint4* d4 = (uint4*)ldsW;
        for (int i = t; i < 384; i += 256) d4[i] = s4[i];
    }
    __syncthreads();
    int wid = t >> 6, lane = t & 63;
    int m = lane & 15, kb = lane >> 4;
    int wr = blockIdx.x * 128 + wid * 32;
    int ra0 = min(wr + m, N - 1);
    int ra1 = min(wr + 16 + m, N - 1);
    f32x4 acc[2][3] = {};
    #pragma unroll
    for (int ks = 0; ks < 2; ++ks) {
        uint4 ua = *(const uint4*)&h[(size_t)ra0 * 32 + ks * 16 + kb * 4];
        uint4 ub = *(const uint4*)&h[(size_t)ra1 * 32 + ks * 16 + kb * 4];
        bf16x8 fa0 = u4_to_bf(ua), fa1 = u4_to_bf(ub);
        #pragma unroll
        for (int ct = 0; ct < 3; ++ct) {
            uint4 wu = *(uint4*)&ldsW[((ct * 2 + ks) * 64 + lane) * 4];
            bf16x8 fb = u4_to_bf(wu);
            acc[0][ct] = __builtin_amdgcn_mfma_f32_16x16x32_bf16(fa0, fb, acc[0][ct], 0, 0, 0);
            acc[1][ct] = __builtin_amdgcn_mfma_f32_16x16x32_bf16(fa1, fb, acc[1][ct], 0, 0, 0);
        }
    }
    int rq = lane >> 4;
    #pragma unroll
    for (int rt = 0; rt < 2; ++rt) {
        float dv[4]; int rows[4];
        #pragma unroll
        for (int j = 0; j < 4; ++j) {
            int r = wr + rt * 16 + rq * 4 + j;
            rows[j] = r;
            dv[j] = dinv[min(r, N - 1)];
        }
        #pragma unroll
        for (int ct = 0; ct < 3; ++ct) {
            #pragma unroll
            for (int j = 0; j < 4; ++j) {
                float v = acc[rt][ct][j] * dv[j];
                float pv = __shfl_xor(v, 1);
                bool colok = (ct < 2) || (m < 8);   // col = ct*16+m < 40
                if (!(lane & 1) && colok && rows[j] < N) {
                    y[(size_t)rows[j] * Y2W + ct * 8 + (m >> 1)] = cvtpk(v, pv);
                }
            }
        }
    }
}

// ---- agg2: grid-stride, 2-deep pipelined gather (packed 20-uint rows, 5 lanes) ----
__global__ __launch_bounds__(256) void agg2_kernel(
    const int* __restrict__ csr, const uint_t* __restrict__ bd,
    const uint_t* __restrict__ y, const float* __restrict__ dinv,
    const float* __restrict__ bias, float* __restrict__ out, int N, int stride)
{
    int w = blockIdx.x * 4 + (threadIdx.x >> 6);
    if (w >= N) return;
    int lane = threadIdx.x & 63;
    int o = lane >> 3, c = lane & 7;
    bool act = (c < 5);

    int n1 = w + stride, n2 = w + 2 * stride;
    uint_t bd0 = bd[w];
    uint_t bd1 = (n1 < N) ? bd[n1] : 0u;
    uint2 idx0;
    {
        int beg0 = MKBEG(w, bd0), end0 = beg0 + (int)(bd0 & 2047u);
        int j0 = beg0 + 2 * o;
        idx0.x = (j0 < end0) ? (uint_t)csr[j0] : 0xFFFFFFFFu;
        idx0.y = (j0 + 1 < end0) ? (uint_t)csr[j0 + 1] : 0xFFFFFFFFu;
    }

    for (int node = w; node < N; ) {
        uint_t bd2 = (n2 < N) ? bd[n2] : 0u;
        uint2 idx1;
        {
            int beg1 = MKBEG(n1, bd1), end1 = beg1 + (int)(bd1 & 2047u);
            int j0 = beg1 + 2 * o;
            idx1.x = (j0 < end1) ? (uint_t)csr[j0] : 0xFFFFFFFFu;
            idx1.y = (j0 + 1 < end1) ? (uint_t)csr[j0 + 1] : 0xFFFFFFFFu;
        }
        f32x2 a[4] = {};
        if (o == 0 && act) {
            uint4 u = *(const uint4*)&y[(size_t)node * Y2W + c * 4];
            ACCP(u);
        }
        if (act && idx0.x != 0xFFFFFFFFu) { uint4 u = *(const uint4*)&y[(size_t)idx0.x * Y2W + c * 4]; ACCP(u); }
        if (act && idx0.y != 0xFFFFFFFFu) { uint4 u = *(const uint4*)&y[(size_t)idx0.y * Y2W + c * 4]; ACCP(u); }
        int beg0 = MKBEG(node, bd0), end0 = beg0 + (int)(bd0 & 2047u);
        for (int j = beg0 + 16; j < end0; j += 16) {
            int j0 = j + 2 * o;
            int i0 = (j0 < end0) ? csr[j0] : -1;
            int i1 = (j0 + 1 < end0) ? csr[j0 + 1] : -1;
            if (act && i0 >= 0) { uint4 u = *(const uint4*)&y[(size_t)i0 * Y2W + c * 4]; ACCP(u); }
            if (act && i1 >= 0) { uint4 u = *(const uint4*)&y[(size_t)i1 * Y2W + c * 4]; ACCP(u); }
        }
        #pragma unroll
        for (int k = 0; k < 4; ++k) {
            a[k].x += __shfl_xor(a[k].x, 8);  a[k].y += __shfl_xor(a[k].y, 8);
            a[k].x += __shfl_xor(a[k].x, 16); a[k].y += __shfl_xor(a[k].y, 16);
            a[k].x += __shfl_xor(a[k].x, 32); a[k].y += __shfl_xor(a[k].y, 32);
        }
        if (o == 0 && act) {
            float di = dinv[node];
            float4 b0 = *(const float4*)&bias[c * 8];
            float4 b1 = *(const float4*)&bias[c * 8 + 4];
            float4 r0, r1;
            r0.x = a[0].x * di + b0.x;
            r0.y = a[0].y * di + b0.y;
            r0.z = a[1].x * di + b0.z;
            r0.w = a[1].y * di + b0.w;
            r1.x = a[2].x * di + b1.x;
            r1.y = a[2].y * di + b1.y;
            r1.z = a[3].x * di + b1.z;
            r1.w = a[3].y * di + b1.w;
            *(float4*)&out[(size_t)node * C_OUT + c * 8] = r0;
            *(float4*)&out[(size_t)node * C_OUT + c * 8 + 4] = r1;
        }
        node = n1; n1 = n2; n2 += stride;
        bd0 = bd1; bd1 = bd2; idx0 = idx1;
    }
}

extern "C" void kernel_launch(void* const* d_in, const int* in_sizes, int n_in,
                              void* d_out, int out_size, void* d_ws, size_t ws_size,
                              hipStream_t stream)
{
    const float* x  = (const float*)d_in[0];
    const int*   ei = (const int*)d_in[1];
    const float* W1 = (const float*)d_in[2];
    const float* b1 = (const float*)d_in[3];
    const float* W2 = (const float*)d_in[4];
    const float* b2 = (const float*)d_in[5];
    float* out = (float*)d_out;

    int N = in_sizes[0] / F_IN;
    int E = in_sizes[1] / 2;
    const int* src = ei;
    const int* dst = ei + E;
    int NB = (N + RB - 1) / RB;
    int K = (E + FILL_CHUNK - 1) / FILL_CHUNK;
    int NBLK = (N + 127) / 128;
    int aggStride = AGG_BLOCKS * 4;

    char* ws = (char*)d_ws;
    uint_t* y1b    = (uint_t*)ws;  ws += (size_t)N * 32 * 4;        // bf16x2 xW1*dinv
    uint_t* y2b    = (uint_t*)ws;  ws += ((size_t)N * Y2W + 8) * 4; // packed bf16x2 hW2*dinv
    uint_t* h1p    = (uint_t*)ws;  ws += (size_t)N * 32 * 4;        // bf16x2 relu'd h
    float* dinv    = (float*)ws;   ws += (size_t)N * 4;
    uint_t* bd     = (uint_t*)ws;  ws += (size_t)N * 4;             // packed (excl<<11)|deg
    int*   hist    = (int*)ws;     ws += (size_t)K * (NB + 1) * 4;
    int*   bm      = (int*)ws;     ws += (size_t)K * FILL_CHUNK * 4;
    int*   csr     = (int*)ws;     ws += (size_t)NB * CAP * 4;
    ushort_t* wb1  = (ushort_t*)ws; ws += 8192 * 2;                 // W1 frag-linear bf16
    ushort_t* wb2  = (ushort_t*)ws; ws += 3072 * 2;                 // W2 frag-linear bf16 (48-pad)

    wconv_kernel<<<44, 256, 0, stream>>>(W1, W2, wb1, wb2);

    bsort_kernel<<<K, FILL_THREADS, 0, stream>>>(src, dst, E, hist, bm, NB);
    csr_gather_kernel<<<NB, 256, 0, stream>>>(hist, bm, K, csr, bd, dinv, N, NB);

    // layer 1
    gemm1_mfma<<<NBLK, 256, 0, stream>>>(x, (const uint_t*)wb1, dinv, y1b, N);
    agg1_kernel<<<AGG_BLOCKS, 256, 0, stream>>>(csr, bd, y1b, dinv, b1, h1p, N, aggStride);

    // layer 2
    gemm2_mfma<<<NBLK, 256, 0, stream>>>(h1p, (const uint_t*)wb2, dinv, y2b, N);
    agg2_kernel<<<AGG_BLOCKS, 256, 0, stream>>>(csr, bd, y2b, dinv, b2, out, N, aggStride);
}

// Round 16
// 148.372 us; speedup vs baseline: 1.0267x; 1.0207x over previous
//
#include <hip/hip_runtime.h>

#define F_IN 128
#define HID 64
#define C_OUT 40

#define RB_SHIFT 6              // 64 nodes per bucket
#define RB 64
#define CAP 1408                // max edges per bucket (mean 1024, +12 sigma)
#define NBMAX 2048
#define FILL_CHUNK 8192         // edges per block in bsort
#define FILL_THREADS 512
#define AGG_BLOCKS 2048

#define MKBEG(node, b) (((node) >> RB_SHIFT) * CAP + (int)((b) >> 11))

typedef unsigned short ushort_t;
typedef unsigned int uint_t;
typedef __attribute__((ext_vector_type(8))) short bf16x8;
typedef __attribute__((ext_vector_type(4))) float f32x4;
typedef __attribute__((ext_vector_type(2))) float f32x2;

__device__ __forceinline__ ushort_t f2bf(float f) {   // RNE bf16 (manual)
    uint_t u = __float_as_uint(f);
    return (ushort_t)((u + 0x7FFF + ((u >> 16) & 1)) >> 16);
}
__device__ __forceinline__ uint_t cvtpk(float lo, float hi) {  // HW RNE pack
    uint_t r;
    asm("v_cvt_pk_bf16_f32 %0, %1, %2" : "=v"(r) : "v"(lo), "v"(hi));
    return r;
}
__device__ __forceinline__ float bf_lo(uint_t u) { return __uint_as_float(u << 16); }
__device__ __forceinline__ float bf_hi(uint_t u) { return __uint_as_float(u & 0xFFFF0000u); }
__device__ __forceinline__ bf16x8 u4_to_bf(uint4 u) {
    union { uint4 a; bf16x8 b; } cv; cv.a = u; return cv.b;
}

// packed accumulate: 4x f32x2 += unpacked pairs (v_pk_add_f32)
#define ACCP(u) { a[0] += (f32x2){bf_lo(u.x), bf_hi(u.x)}; \
                  a[1] += (f32x2){bf_lo(u.y), bf_hi(u.y)}; \
                  a[2] += (f32x2){bf_lo(u.z), bf_hi(u.z)}; \
                  a[3] += (f32x2){bf_lo(u.w), bf_hi(u.w)}; }

// ---- per-chunk bucket sort into PRIVATE region; offsets to hist (no global atomics) ----
__global__ __launch_bounds__(FILL_THREADS) void bsort_kernel(
    const int* __restrict__ src, const int* __restrict__ dst, int E,
    int* __restrict__ hist, int* __restrict__ bm, int NB)
{
    __shared__ int lcnt[NBMAX];
    __shared__ int loff[NBMAX];
    __shared__ int wsum[8];
    int t = threadIdx.x;
    for (int i = t; i < NBMAX; i += FILL_THREADS) lcnt[i] = 0;
    __syncthreads();
    int base = blockIdx.x * FILL_CHUNK;
    int nE = min(E - base, FILL_CHUNK);
    #pragma unroll
    for (int k = 0; k < FILL_CHUNK / FILL_THREADS; ++k) {
        int e = k * FILL_THREADS + t;
        if (e < nE) atomicAdd(&lcnt[dst[base + e] >> RB_SHIFT], 1);
    }
    __syncthreads();
    {
        int v[4]; int tsum = 0;
        #pragma unroll
        for (int i = 0; i < 4; ++i) { v[i] = lcnt[t * 4 + i]; tsum += v[i]; }
        int lane = t & 63, wid = t >> 6;
        int incl = tsum;
        #pragma unroll
        for (int off = 1; off < 64; off <<= 1) {
            int u = __shfl_up(incl, off);
            if (lane >= off) incl += u;
        }
        if (lane == 63) wsum[wid] = incl;
        __syncthreads();
        if (t < 8) {
            int wv = wsum[t];
            int wincl = wv;
            #pragma unroll
            for (int off = 1; off < 8; off <<= 1) {
                int u = __shfl_up(wincl, off);
                if (t >= off) wincl += u;
            }
            wsum[t] = wincl - wv;
        }
        __syncthreads();
        int run = wsum[wid] + incl - tsum;
        #pragma unroll
        for (int i = 0; i < 4; ++i) { loff[t * 4 + i] = run; run += v[i]; }
    }
    __syncthreads();
    long long hrow = (long long)blockIdx.x * (NB + 1);
    for (int i = t; i < NB; i += FILL_THREADS) hist[hrow + i] = loff[i];
    if (t == 0) hist[hrow + NB] = nE;
    __syncthreads();
    #pragma unroll
    for (int k = 0; k < FILL_CHUNK / FILL_THREADS; ++k) {
        int e = k * FILL_THREADS + t;
        if (e < nE) {
            int d = dst[base + e], s = src[base + e];
            int b = d >> RB_SHIFT;
            int pos = atomicAdd(&loff[b], 1);
            bm[base + pos] = (s << RB_SHIFT) | (d & (RB - 1));
        }
    }
}

// ---- gather bucket's runs; per-node counting sort -> CSR + packed (excl,deg) + dinv ----
__global__ __launch_bounds__(256) void csr_gather_kernel(
    const int* __restrict__ hist, const int* __restrict__ bm, int K,
    int* __restrict__ csr, uint_t* __restrict__ bd,
    float* __restrict__ dinv, int N, int NB)
{
    __shared__ int staging[CAP];
    __shared__ int histo[RB];
    __shared__ int cursor[RB];
    __shared__ int waux[8];
    int t = threadIdx.x;
    int b = blockIdx.x;
    int len = 0, st = 0;
    if (t < K) {
        long long hrow = (long long)t * (NB + 1);
        st = hist[hrow + b];
        len = hist[hrow + b + 1] - st;
    }
    int lane = t & 63, wid = t >> 6;
    int incl = len;
    #pragma unroll
    for (int off = 1; off < 64; off <<= 1) {
        int u = __shfl_up(incl, off);
        if (lane >= off) incl += u;
    }
    if (lane == 63) waux[wid] = incl;
    if (t < RB) histo[t] = 0;
    __syncthreads();
    if (t < 4) {
        int w = waux[t];
        int wincl = w;
        #pragma unroll
        for (int off = 1; off < 4; off <<= 1) {
            int u = __shfl_up(wincl, off);
            if (t >= off) wincl += u;
        }
        waux[t] = wincl - w;
        if (t == 3) waux[4] = wincl;
    }
    __syncthreads();
    int bpos = waux[wid] + incl - len;
    int cnt = waux[4];
    if (cnt > CAP) cnt = CAP;
    if (t < K && len > 0) {
        int gbase = t * FILL_CHUNK + st;
        for (int i = 0; i < len; ++i) {
            int p = bpos + i;
            if (p < CAP) staging[p] = bm[gbase + i];
        }
    }
    __syncthreads();
    for (int i = t; i < cnt; i += 256) atomicAdd(&histo[staging[i] & (RB - 1)], 1);
    __syncthreads();
    if (t < RB) {
        int v = histo[t];
        int nincl = v;
        #pragma unroll
        for (int off = 1; off < 64; off <<= 1) {
            int u = __shfl_up(nincl, off);
            if (t >= off) nincl += u;
        }
        int excl = nincl - v;
        cursor[t] = excl;
        int node = b * RB + t;
        if (node < N) {
            bd[node] = ((uint_t)excl << 11) | (uint_t)v;
            dinv[node] = rsqrtf((float)(v + 1));   // +1 self-loop
        }
    }
    __syncthreads();
    int cbase = b * CAP;
    for (int i = t; i < cnt; i += 256) {
        int e = staging[i];
        int n = e & (RB - 1);
        int r = atomicAdd(&cursor[n], 1);
        csr[cbase + r] = e >> RB_SHIFT;
    }
}

// ---- W1 & W2 -> fragment-linear bf16 ----
__global__ void wconv_kernel(const float* __restrict__ W1, const float* __restrict__ W2,
                             ushort_t* __restrict__ wb1, ushort_t* __restrict__ wb2)
{
    int tid = blockIdx.x * 256 + threadIdx.x;
    if (tid < 8192) {
        int j = tid & 7, l = (tid >> 3) & 63, ks = (tid >> 9) & 3, ct = tid >> 11;
        int c = ct * 16 + (l & 15);
        int k = ks * 32 + (l >> 4) * 8 + j;
        wb1[tid] = f2bf(W1[k * HID + c]);
    } else if (tid < 8192 + 3072) {
        int s = tid - 8192;
        int j = s & 7, l = (s >> 3) & 63, ks = (s >> 9) & 1, ct = s >> 10;
        int c = ct * 16 + (l & 15);
        int k = ks * 32 + (l >> 4) * 8 + j;
        wb2[s] = (c < C_OUT) ? f2bf(W2[k * C_OUT + c]) : (ushort_t)0;
    }
}

// ---- GEMM1 (MFMA): y[N,32 uints] = bf16pack((x @ W1) * dinv[row]) ----
__global__ __launch_bounds__(256) void gemm1_mfma(
    const float* __restrict__ x, const uint_t* __restrict__ Wb,
    const float* __restrict__ dinv, uint_t* __restrict__ y, int N)
{
    __shared__ uint_t ldsW[4096];   // 16 KB
    int t = threadIdx.x;
    {
        const uint4* s4 = (const uint4*)Wb;
        uint4* d4 = (uint4*)ldsW;
        for (int i = t; i < 1024; i += 256) d4[i] = s4[i];
    }
    __syncthreads();
    int wid = t >> 6, lane = t & 63;
    int m = lane & 15, kb = lane >> 4;
    int wr = blockIdx.x * 128 + wid * 32;
    int ra0 = min(wr + m, N - 1);
    int ra1 = min(wr + 16 + m, N - 1);
    f32x4 acc[2][4] = {};
    #pragma unroll
    for (int ks = 0; ks < 4; ++ks) {
        const float* p0 = &x[(size_t)ra0 * F_IN + ks * 32 + kb * 8];
        const float* p1 = &x[(size_t)ra1 * F_IN + ks * 32 + kb * 8];
        float4 a0 = *(const float4*)p0, a1 = *(const float4*)(p0 + 4);
        float4 c0 = *(const float4*)p1, c1 = *(const float4*)(p1 + 4);
        uint4 ua = make_uint4(cvtpk(a0.x, a0.y), cvtpk(a0.z, a0.w),
                              cvtpk(a1.x, a1.y), cvtpk(a1.z, a1.w));
        uint4 ub = make_uint4(cvtpk(c0.x, c0.y), cvtpk(c0.z, c0.w),
                              cvtpk(c1.x, c1.y), cvtpk(c1.z, c1.w));
        bf16x8 fa0 = u4_to_bf(ua), fa1 = u4_to_bf(ub);
        #pragma unroll
        for (int ct = 0; ct < 4; ++ct) {
            uint4 wu = *(uint4*)&ldsW[((ct * 4 + ks) * 64 + lane) * 4];
            bf16x8 fb = u4_to_bf(wu);
            acc[0][ct] = __builtin_amdgcn_mfma_f32_16x16x32_bf16(fa0, fb, acc[0][ct], 0, 0, 0);
            acc[1][ct] = __builtin_amdgcn_mfma_f32_16x16x32_bf16(fa1, fb, acc[1][ct], 0, 0, 0);
        }
    }
    int rq = lane >> 4;
    #pragma unroll
    for (int rt = 0; rt < 2; ++rt) {
        float dv[4]; int rows[4];
        #pragma unroll
        for (int j = 0; j < 4; ++j) {
            int r = wr + rt * 16 + rq * 4 + j;
            rows[j] = r;
            dv[j] = dinv[min(r, N - 1)];
        }
        #pragma unroll
        for (int ct = 0; ct < 4; ++ct) {
            #pragma unroll
            for (int j = 0; j < 4; ++j) {
                float v = acc[rt][ct][j] * dv[j];
                float pv = __shfl_xor(v, 1);
                if (!(lane & 1) && rows[j] < N) {
                    y[(size_t)rows[j] * 32 + ct * 8 + (m >> 1)] = cvtpk(v, pv);
                }
            }
        }
    }
}

// ---- agg1: rolling-window prefetch gather; h(bf16) = relu((sum+self)*dinv+b) ----
__global__ __launch_bounds__(256) void agg1_kernel(
    const int* __restrict__ csr, const uint_t* __restrict__ bd,
    const uint_t* __restrict__ y, const float* __restrict__ dinv,
    const float* __restrict__ bias, uint_t* __restrict__ h, int N, int stride)
{
    int w = blockIdx.x * 4 + (threadIdx.x >> 6);
    if (w >= N) return;
    int lane = threadIdx.x & 63;
    int o = lane >> 3, c = lane & 7;
    int so = 2 * o;

    int n1 = w + stride, n2 = w + 2 * stride;
    uint_t bd0 = bd[w];
    uint_t bd1 = (n1 < N) ? bd[n1] : 0u;
    uint2 idx0;
    {
        int beg0 = MKBEG(w, bd0); int d0 = (int)(bd0 & 2047u);
        idx0.x = (so < d0) ? (uint_t)csr[beg0 + so] : 0xFFFFFFFFu;
        idx0.y = (so + 1 < d0) ? (uint_t)csr[beg0 + so + 1] : 0xFFFFFFFFu;
    }

    for (int node = w; node < N; ) {
        uint_t bd2 = (n2 < N) ? bd[n2] : 0u;          // prefetch bd +2
        uint2 idx1;                                    // prefetch next node window 0
        {
            int beg1 = MKBEG(n1, bd1); int d1 = (int)(bd1 & 2047u);
            idx1.x = (so < d1) ? (uint_t)csr[beg1 + so] : 0xFFFFFFFFu;
            idx1.y = (so + 1 < d1) ? (uint_t)csr[beg1 + so + 1] : 0xFFFFFFFFu;
        }
        int deg0 = (int)(bd0 & 2047u);
        int beg0 = MKBEG(node, bd0);
        f32x2 a[4] = {};
        if (o == 0) {
            uint4 u = *(const uint4*)&y[(size_t)node * 32 + c * 4];
            ACCP(u);
        }
        uint2 cur = idx0;
        int j = 16;
        for (;;) {
            uint2 nxt = make_uint2(0xFFFFFFFFu, 0xFFFFFFFFu);
            bool more = (j < deg0);
            if (more) {                                // issue next window BEFORE gathers
                int s = j + so;
                nxt.x = (s < deg0) ? (uint_t)csr[beg0 + s] : 0xFFFFFFFFu;
                nxt.y = (s + 1 < deg0) ? (uint_t)csr[beg0 + s + 1] : 0xFFFFFFFFu;
            }
            if (cur.x != 0xFFFFFFFFu) { uint4 u = *(const uint4*)&y[(size_t)cur.x * 32 + c * 4]; ACCP(u); }
            if (cur.y != 0xFFFFFFFFu) { uint4 u = *(const uint4*)&y[(size_t)cur.y * 32 + c * 4]; ACCP(u); }
            if (!more) break;
            cur = nxt; j += 16;
        }
        #pragma unroll
        for (int k = 0; k < 4; ++k) {
            a[k].x += __shfl_xor(a[k].x, 8);  a[k].y += __shfl_xor(a[k].y, 8);
            a[k].x += __shfl_xor(a[k].x, 16); a[k].y += __shfl_xor(a[k].y, 16);
            a[k].x += __shfl_xor(a[k].x, 32); a[k].y += __shfl_xor(a[k].y, 32);
        }
        if (o == 0) {
            float di = dinv[node];
            float4 b0 = *(const float4*)&bias[c * 8];
            float4 b1 = *(const float4*)&bias[c * 8 + 4];
            float o0 = fmaxf(a[0].x * di + b0.x, 0.f);
            float o1 = fmaxf(a[0].y * di + b0.y, 0.f);
            float o2 = fmaxf(a[1].x * di + b0.z, 0.f);
            float o3 = fmaxf(a[1].y * di + b0.w, 0.f);
            float o4 = fmaxf(a[2].x * di + b1.x, 0.f);
            float o5 = fmaxf(a[2].y * di + b1.y, 0.f);
            float o6 = fmaxf(a[3].x * di + b1.z, 0.f);
            float o7 = fmaxf(a[3].y * di + b1.w, 0.f);
            uint4 r = make_uint4(cvtpk(o0, o1), cvtpk(o2, o3), cvtpk(o4, o5), cvtpk(o6, o7));
            *(uint4*)&h[(size_t)node * 32 + c * 4] = r;
        }
        node = n1; n1 = n2; n2 += stride;
        bd0 = bd1; bd1 = bd2; idx0 = idx1;
    }
}

// ---- GEMM2 (MFMA): y2[N,32 uints, cols 0..39] = bf16pack((h @ W2) * dinv[row]) ----
__global__ __launch_bounds__(256) void gemm2_mfma(
    const uint_t* __restrict__ h, const uint_t* __restrict__ Wb,
    const float* __restrict__ dinv, uint_t* __restrict__ y, int N)
{
    __shared__ uint_t ldsW[1536];   // 6 KB
    int t = threadIdx.x;
    {
        const uint4* s4 = (const uint4*)Wb;
        uint4* d4 = (uint4*)ldsW;
        for (int i = t; i < 384; i += 256) d4[i] = s4[i];
    }
    __syncthreads();
    int wid = t >> 6, lane = t & 63;
    int m = lane & 15, kb = lane >> 4;
    int wr = blockIdx.x * 128 + wid * 32;
    int ra0 = min(wr + m, N - 1);
    int ra1 = min(wr + 16 + m, N - 1);
    f32x4 acc[2][3] = {};
    #pragma unroll
    for (int ks = 0; ks < 2; ++ks) {
        uint4 ua = *(const uint4*)&h[(size_t)ra0 * 32 + ks * 16 + kb * 4];
        uint4 ub = *(const uint4*)&h[(size_t)ra1 * 32 + ks * 16 + kb * 4];
        bf16x8 fa0 = u4_to_bf(ua), fa1 = u4_to_bf(ub);
        #pragma unroll
        for (int ct = 0; ct < 3; ++ct) {
            uint4 wu = *(uint4*)&ldsW[((ct * 2 + ks) * 64 + lane) * 4];
            bf16x8 fb = u4_to_bf(wu);
            acc[0][ct] = __builtin_amdgcn_mfma_f32_16x16x32_bf16(fa0, fb, acc[0][ct], 0, 0, 0);
            acc[1][ct] = __builtin_amdgcn_mfma_f32_16x16x32_bf16(fa1, fb, acc[1][ct], 0, 0, 0);
        }
    }
    int rq = lane >> 4;
    #pragma unroll
    for (int rt = 0; rt < 2; ++rt) {
        float dv[4]; int rows[4];
        #pragma unroll
        for (int j = 0; j < 4; ++j) {
            int r = wr + rt * 16 + rq * 4 + j;
            rows[j] = r;
            dv[j] = dinv[min(r, N - 1)];
        }
        #pragma unroll
        for (int ct = 0; ct < 3; ++ct) {
            #pragma unroll
            for (int j = 0; j < 4; ++j) {
                float v = acc[rt][ct][j] * dv[j];
                float pv = __shfl_xor(v, 1);
                bool colok = (ct < 2) || (m < 8);   // col = ct*16+m < 40
                if (!(lane & 1) && colok && rows[j] < N) {
                    y[(size_t)rows[j] * 32 + ct * 8 + (m >> 1)] = cvtpk(v, pv);
                }
            }
        }
    }
}

// ---- agg2: rolling-window prefetch gather (5 active uint4 lanes) ----
__global__ __launch_bounds__(256) void agg2_kernel(
    const int* __restrict__ csr, const uint_t* __restrict__ bd,
    const uint_t* __restrict__ y, const float* __restrict__ dinv,
    const float* __restrict__ bias, float* __restrict__ out, int N, int stride)
{
    int w = blockIdx.x * 4 + (threadIdx.x >> 6);
    if (w >= N) return;
    int lane = threadIdx.x & 63;
    int o = lane >> 3, c = lane & 7;
    int so = 2 * o;
    bool act = (c < 5);

    int n1 = w + stride, n2 = w + 2 * stride;
    uint_t bd0 = bd[w];
    uint_t bd1 = (n1 < N) ? bd[n1] : 0u;
    uint2 idx0;
    {
        int beg0 = MKBEG(w, bd0); int d0 = (int)(bd0 & 2047u);
        idx0.x = (so < d0) ? (uint_t)csr[beg0 + so] : 0xFFFFFFFFu;
        idx0.y = (so + 1 < d0) ? (uint_t)csr[beg0 + so + 1] : 0xFFFFFFFFu;
    }

    for (int node = w; node < N; ) {
        uint_t bd2 = (n2 < N) ? bd[n2] : 0u;
        uint2 idx1;
        {
            int beg1 = MKBEG(n1, bd1); int d1 = (int)(bd1 & 2047u);
            idx1.x = (so < d1) ? (uint_t)csr[beg1 + so] : 0xFFFFFFFFu;
            idx1.y = (so + 1 < d1) ? (uint_t)csr[beg1 + so + 1] : 0xFFFFFFFFu;
        }
        int deg0 = (int)(bd0 & 2047u);
        int beg0 = MKBEG(node, bd0);
        f32x2 a[4] = {};
        if (o == 0 && act) {
            uint4 u = *(const uint4*)&y[(size_t)node * 32 + c * 4];
            ACCP(u);
        }
        uint2 cur = idx0;
        int j = 16;
        for (;;) {
            uint2 nxt = make_uint2(0xFFFFFFFFu, 0xFFFFFFFFu);
            bool more = (j < deg0);
            if (more) {
                int s = j + so;
                nxt.x = (s < deg0) ? (uint_t)csr[beg0 + s] : 0xFFFFFFFFu;
                nxt.y = (s + 1 < deg0) ? (uint_t)csr[beg0 + s + 1] : 0xFFFFFFFFu;
            }
            if (act && cur.x != 0xFFFFFFFFu) { uint4 u = *(const uint4*)&y[(size_t)cur.x * 32 + c * 4]; ACCP(u); }
            if (act && cur.y != 0xFFFFFFFFu) { uint4 u = *(const uint4*)&y[(size_t)cur.y * 32 + c * 4]; ACCP(u); }
            if (!more) break;
            cur = nxt; j += 16;
        }
        #pragma unroll
        for (int k = 0; k < 4; ++k) {
            a[k].x += __shfl_xor(a[k].x, 8);  a[k].y += __shfl_xor(a[k].y, 8);
            a[k].x += __shfl_xor(a[k].x, 16); a[k].y += __shfl_xor(a[k].y, 16);
            a[k].x += __shfl_xor(a[k].x, 32); a[k].y += __shfl_xor(a[k].y, 32);
        }
        if (o == 0 && act) {
            float di = dinv[node];
            float4 b0 = *(const float4*)&bias[c * 8];
            float4 b1 = *(const float4*)&bias[c * 8 + 4];
            float4 r0, r1;
            r0.x = a[0].x * di + b0.x;
            r0.y = a[0].y * di + b0.y;
            r0.z = a[1].x * di + b0.z;
            r0.w = a[1].y * di + b0.w;
            r1.x = a[2].x * di + b1.x;
            r1.y = a[2].y * di + b1.y;
            r1.z = a[3].x * di + b1.z;
            r1.w = a[3].y * di + b1.w;
            *(float4*)&out[(size_t)node * C_OUT + c * 8] = r0;
            *(float4*)&out[(size_t)node * C_OUT + c * 8 + 4] = r1;
        }
        node = n1; n1 = n2; n2 += stride;
        bd0 = bd1; bd1 = bd2; idx0 = idx1;
    }
}

extern "C" void kernel_launch(void* const* d_in, const int* in_sizes, int n_in,
                              void* d_out, int out_size, void* d_ws, size_t ws_size,
                              hipStream_t stream)
{
    const float* x  = (const float*)d_in[0];
    const int*   ei = (const int*)d_in[1];
    const float* W1 = (const float*)d_in[2];
    const float* b1 = (const float*)d_in[3];
    const float* W2 = (const float*)d_in[4];
    const float* b2 = (const float*)d_in[5];
    float* out = (float*)d_out;

    int N = in_sizes[0] / F_IN;
    int E = in_sizes[1] / 2;
    const int* src = ei;
    const int* dst = ei + E;
    int NB = (N + RB - 1) / RB;
    int K = (E + FILL_CHUNK - 1) / FILL_CHUNK;
    int NBLK = (N + 127) / 128;
    int aggStride = AGG_BLOCKS * 4;

    char* ws = (char*)d_ws;
    uint_t* y1b    = (uint_t*)ws;  ws += (size_t)N * 32 * 4;   // bf16x2 xW1*dinv
    uint_t* y2b    = (uint_t*)ws;  ws += (size_t)N * 32 * 4;   // bf16x2 hW2*dinv
    uint_t* h1p    = (uint_t*)ws;  ws += (size_t)N * 32 * 4;   // bf16x2 relu'd h
    float* dinv    = (float*)ws;   ws += (size_t)N * 4;
    uint_t* bd     = (uint_t*)ws;  ws += (size_t)N * 4;        // packed (excl<<11)|deg
    int*   hist    = (int*)ws;     ws += (size_t)K * (NB + 1) * 4;
    int*   bm      = (int*)ws;     ws += (size_t)K * FILL_CHUNK * 4;
    int*   csr     = (int*)ws;     ws += (size_t)NB * CAP * 4;
    ushort_t* wb1  = (ushort_t*)ws; ws += 8192 * 2;            // W1 frag-linear bf16
    ushort_t* wb2  = (ushort_t*)ws; ws += 3072 * 2;            // W2 frag-linear bf16 (48-pad)

    wconv_kernel<<<44, 256, 0, stream>>>(W1, W2, wb1, wb2);

    bsort_kernel<<<K, FILL_THREADS, 0, stream>>>(src, dst, E, hist, bm, NB);
    csr_gather_kernel<<<NB, 256, 0, stream>>>(hist, bm, K, csr, bd, dinv, N, NB);

    // layer 1
    gemm1_mfma<<<NBLK, 256, 0, stream>>>(x, (const uint_t*)wb1, dinv, y1b, N);
    agg1_kernel<<<AGG_BLOCKS, 256, 0, stream>>>(csr, bd, y1b, dinv, b1, h1p, N, aggStride);

    // layer 2
    gemm2_mfma<<<NBLK, 256, 0, stream>>>(h1p, (const uint_t*)wb2, dinv, y2b, N);
    agg2_kernel<<<AGG_BLOCKS, 256, 0, stream>>>(csr, bd, y2b, dinv, b2, out, N, aggStride);
}

// Round 17
// 141.465 us; speedup vs baseline: 1.0768x; 1.0488x over previous
//
#include <hip/hip_runtime.h>

#define F_IN 128
#define HID 64
#define C_OUT 40

#define RB_SHIFT 6              // 64 nodes per bucket
#define RB 64
#define CAP 2176                // padded edges per bucket (mult of 16)
#define NBMAX 2048
#define FILL_CHUNK 8192         // edges per block in bsort
#define FILL_THREADS 512
#define AGG_BLOCKS 2048

// bd = ((excl/16) << 8) | nw   (excl mult of 16; nw = padded windows of 16)
#define MKBEG(node, b) (((node) >> RB_SHIFT) * CAP + (((int)((b) >> 8)) << 4))
#define NWIN(b) ((int)((b) & 255u))

typedef unsigned short ushort_t;
typedef unsigned int uint_t;
typedef __attribute__((ext_vector_type(8))) short bf16x8;
typedef __attribute__((ext_vector_type(4))) float f32x4;
typedef __attribute__((ext_vector_type(2))) float f32x2;

__device__ __forceinline__ ushort_t f2bf(float f) {   // RNE bf16 (manual)
    uint_t u = __float_as_uint(f);
    return (ushort_t)((u + 0x7FFF + ((u >> 16) & 1)) >> 16);
}
__device__ __forceinline__ uint_t cvtpk(float lo, float hi) {  // HW RNE pack
    uint_t r;
    asm("v_cvt_pk_bf16_f32 %0, %1, %2" : "=v"(r) : "v"(lo), "v"(hi));
    return r;
}
__device__ __forceinline__ float bf_lo(uint_t u) { return __uint_as_float(u << 16); }
__device__ __forceinline__ float bf_hi(uint_t u) { return __uint_as_float(u & 0xFFFF0000u); }
__device__ __forceinline__ bf16x8 u4_to_bf(uint4 u) {
    union { uint4 a; bf16x8 b; } cv; cv.a = u; return cv.b;
}

// packed accumulate: 4x f32x2 += unpacked pairs (v_pk_add_f32)
#define ACCP(u) { a[0] += (f32x2){bf_lo(u.x), bf_hi(u.x)}; \
                  a[1] += (f32x2){bf_lo(u.y), bf_hi(u.y)}; \
                  a[2] += (f32x2){bf_lo(u.z), bf_hi(u.z)}; \
                  a[3] += (f32x2){bf_lo(u.w), bf_hi(u.w)}; }

// ---- per-chunk bucket sort into PRIVATE region; offsets to hist (no global atomics) ----
__global__ __launch_bounds__(FILL_THREADS) void bsort_kernel(
    const int* __restrict__ src, const int* __restrict__ dst, int E,
    int* __restrict__ hist, int* __restrict__ bm, int NB)
{
    __shared__ int lcnt[NBMAX];
    __shared__ int loff[NBMAX];
    __shared__ int wsum[8];
    int t = threadIdx.x;
    for (int i = t; i < NBMAX; i += FILL_THREADS) lcnt[i] = 0;
    __syncthreads();
    int base = blockIdx.x * FILL_CHUNK;
    int nE = min(E - base, FILL_CHUNK);
    #pragma unroll
    for (int k = 0; k < FILL_CHUNK / FILL_THREADS; ++k) {
        int e = k * FILL_THREADS + t;
        if (e < nE) atomicAdd(&lcnt[dst[base + e] >> RB_SHIFT], 1);
    }
    __syncthreads();
    {
        int v[4]; int tsum = 0;
        #pragma unroll
        for (int i = 0; i < 4; ++i) { v[i] = lcnt[t * 4 + i]; tsum += v[i]; }
        int lane = t & 63, wid = t >> 6;
        int incl = tsum;
        #pragma unroll
        for (int off = 1; off < 64; off <<= 1) {
            int u = __shfl_up(incl, off);
            if (lane >= off) incl += u;
        }
        if (lane == 63) wsum[wid] = incl;
        __syncthreads();
        if (t < 8) {
            int wv = wsum[t];
            int wincl = wv;
            #pragma unroll
            for (int off = 1; off < 8; off <<= 1) {
                int u = __shfl_up(wincl, off);
                if (t >= off) wincl += u;
            }
            wsum[t] = wincl - wv;
        }
        __syncthreads();
        int run = wsum[wid] + incl - tsum;
        #pragma unroll
        for (int i = 0; i < 4; ++i) { loff[t * 4 + i] = run; run += v[i]; }
    }
    __syncthreads();
    long long hrow = (long long)blockIdx.x * (NB + 1);
    for (int i = t; i < NB; i += FILL_THREADS) hist[hrow + i] = loff[i];
    if (t == 0) hist[hrow + NB] = nE;
    __syncthreads();
    #pragma unroll
    for (int k = 0; k < FILL_CHUNK / FILL_THREADS; ++k) {
        int e = k * FILL_THREADS + t;
        if (e < nE) {
            int d = dst[base + e], s = src[base + e];
            int b = d >> RB_SHIFT;
            int pos = atomicAdd(&loff[b], 1);
            bm[base + pos] = (s << RB_SHIFT) | (d & (RB - 1));
        }
    }
}

// ---- gather bucket's runs; counting sort w/ 16-edge-padded segments, dummy idx = N ----
__global__ __launch_bounds__(256) void csr_gather_kernel(
    const int* __restrict__ hist, const int* __restrict__ bm, int K,
    int* __restrict__ csr, uint_t* __restrict__ bd,
    float* __restrict__ dinv, int N, int NB)
{
    __shared__ int staging[CAP];
    __shared__ int histo[RB];
    __shared__ int cursor[RB];
    __shared__ int waux[8];
    int t = threadIdx.x;
    int b = blockIdx.x;
    int len = 0, st = 0;
    if (t < K) {
        long long hrow = (long long)t * (NB + 1);
        st = hist[hrow + b];
        len = hist[hrow + b + 1] - st;
    }
    int lane = t & 63, wid = t >> 6;
    int incl = len;
    #pragma unroll
    for (int off = 1; off < 64; off <<= 1) {
        int u = __shfl_up(incl, off);
        if (lane >= off) incl += u;
    }
    if (lane == 63) waux[wid] = incl;
    if (t < RB) histo[t] = 0;
    __syncthreads();
    if (t < 4) {
        int w = waux[t];
        int wincl = w;
        #pragma unroll
        for (int off = 1; off < 4; off <<= 1) {
            int u = __shfl_up(wincl, off);
            if (t >= off) wincl += u;
        }
        waux[t] = wincl - w;
        if (t == 3) waux[4] = wincl;
    }
    __syncthreads();
    int bpos = waux[wid] + incl - len;
    int cnt = waux[4];
    if (cnt > CAP) cnt = CAP;
    if (t < K && len > 0) {
        int gbase = t * FILL_CHUNK + st;
        for (int i = 0; i < len; ++i) {
            int p = bpos + i;
            if (p < CAP) staging[p] = bm[gbase + i];
        }
    }
    __syncthreads();
    for (int i = t; i < cnt; i += 256) atomicAdd(&histo[staging[i] & (RB - 1)], 1);
    __syncthreads();
    if (t < RB) {
        int v = histo[t];
        int vv = v ? v : 1;
        int pv = (vv + 15) & ~15;          // padded segment, >=16, mult of 16
        int nincl = pv;
        #pragma unroll
        for (int off = 1; off < 64; off <<= 1) {
            int u = __shfl_up(nincl, off);
            if (t >= off) nincl += u;
        }
        int excl = nincl - pv;             // multiple of 16
        cursor[t] = excl;
        if (t == 63) waux[5] = (nincl <= CAP) ? nincl : CAP;
        int node = b * RB + t;
        if (node < N) {
            bd[node] = ((uint_t)(excl >> 4) << 8) | (uint_t)(pv >> 4);
            dinv[node] = rsqrtf((float)(v + 1));   // +1 self-loop
        }
    }
    __syncthreads();
    int cbase = b * CAP;
    int totp = waux[5];
    for (int i = t; i < totp; i += 256) csr[cbase + i] = N;   // dummy-fill padded region
    __syncthreads();
    for (int i = t; i < cnt; i += 256) {
        int e = staging[i];
        int n = e & (RB - 1);
        int r = atomicAdd(&cursor[n], 1);
        if (r < CAP) csr[cbase + r] = e >> RB_SHIFT;
    }
}

// ---- W1 & W2 -> fragment-linear bf16; zero dummy rows of y1b/y2b ----
__global__ void wconv_kernel(const float* __restrict__ W1, const float* __restrict__ W2,
                             ushort_t* __restrict__ wb1, ushort_t* __restrict__ wb2,
                             uint_t* __restrict__ y1b, uint_t* __restrict__ y2b, int N)
{
    int tid = blockIdx.x * 256 + threadIdx.x;
    if (blockIdx.x == 0 && threadIdx.x < 32) {
        y1b[(size_t)N * 32 + threadIdx.x] = 0u;   // dummy row for agg1
        y2b[(size_t)N * 32 + threadIdx.x] = 0u;   // dummy row for agg2
    }
    if (tid < 8192) {
        int j = tid & 7, l = (tid >> 3) & 63, ks = (tid >> 9) & 3, ct = tid >> 11;
        int c = ct * 16 + (l & 15);
        int k = ks * 32 + (l >> 4) * 8 + j;
        wb1[tid] = f2bf(W1[k * HID + c]);
    } else if (tid < 8192 + 3072) {
        int s = tid - 8192;
        int j = s & 7, l = (s >> 3) & 63, ks = (s >> 9) & 1, ct = s >> 10;
        int c = ct * 16 + (l & 15);
        int k = ks * 32 + (l >> 4) * 8 + j;
        wb2[s] = (c < C_OUT) ? f2bf(W2[k * C_OUT + c]) : (ushort_t)0;
    }
}

// ---- GEMM1 (MFMA): y[N,32 uints] = bf16pack((x @ W1) * dinv[row]) ----
__global__ __launch_bounds__(256) void gemm1_mfma(
    const float* __restrict__ x, const uint_t* __restrict__ Wb,
    const float* __restrict__ dinv, uint_t* __restrict__ y, int N)
{
    __shared__ uint_t ldsW[4096];   // 16 KB
    int t = threadIdx.x;
    {
        const uint4* s4 = (const uint4*)Wb;
        uint4* d4 = (uint4*)ldsW;
        for (int i = t; i < 1024; i += 256) d4[i] = s4[i];
    }
    __syncthreads();
    int wid = t >> 6, lane = t & 63;
    int m = lane & 15, kb = lane >> 4;
    int wr = blockIdx.x * 128 + wid * 32;
    int ra0 = min(wr + m, N - 1);
    int ra1 = min(wr + 16 + m, N - 1);
    f32x4 acc[2][4] = {};
    #pragma unroll
    for (int ks = 0; ks < 4; ++ks) {
        const float* p0 = &x[(size_t)ra0 * F_IN + ks * 32 + kb * 8];
        const float* p1 = &x[(size_t)ra1 * F_IN + ks * 32 + kb * 8];
        float4 a0 = *(const float4*)p0, a1 = *(const float4*)(p0 + 4);
        float4 c0 = *(const float4*)p1, c1 = *(const float4*)(p1 + 4);
        uint4 ua = make_uint4(cvtpk(a0.x, a0.y), cvtpk(a0.z, a0.w),
                              cvtpk(a1.x, a1.y), cvtpk(a1.z, a1.w));
        uint4 ub = make_uint4(cvtpk(c0.x, c0.y), cvtpk(c0.z, c0.w),
                              cvtpk(c1.x, c1.y), cvtpk(c1.z, c1.w));
        bf16x8 fa0 = u4_to_bf(ua), fa1 = u4_to_bf(ub);
        #pragma unroll
        for (int ct = 0; ct < 4; ++ct) {
            uint4 wu = *(uint4*)&ldsW[((ct * 4 + ks) * 64 + lane) * 4];
            bf16x8 fb = u4_to_bf(wu);
            acc[0][ct] = __builtin_amdgcn_mfma_f32_16x16x32_bf16(fa0, fb, acc[0][ct], 0, 0, 0);
            acc[1][ct] = __builtin_amdgcn_mfma_f32_16x16x32_bf16(fa1, fb, acc[1][ct], 0, 0, 0);
        }
    }
    int rq = lane >> 4;
    #pragma unroll
    for (int rt = 0; rt < 2; ++rt) {
        float dv[4]; int rows[4];
        #pragma unroll
        for (int j = 0; j < 4; ++j) {
            int r = wr + rt * 16 + rq * 4 + j;
            rows[j] = r;
            dv[j] = dinv[min(r, N - 1)];
        }
        #pragma unroll
        for (int ct = 0; ct < 4; ++ct) {
            #pragma unroll
            for (int j = 0; j < 4; ++j) {
                float v = acc[rt][ct][j] * dv[j];
                float pv = __shfl_xor(v, 1);
                if (!(lane & 1) && rows[j] < N) {
                    y[(size_t)rows[j] * 32 + ct * 8 + (m >> 1)] = cvtpk(v, pv);
                }
            }
        }
    }
}

// ---- agg1: unconditional padded-window gather; h(bf16) = relu((sum+self)*dinv+b) ----
__global__ __launch_bounds__(256) void agg1_kernel(
    const int* __restrict__ csr, const uint_t* __restrict__ bd,
    const uint_t* __restrict__ y, const float* __restrict__ dinv,
    const float* __restrict__ bias, uint_t* __restrict__ h, int N, int stride)
{
    int w = blockIdx.x * 4 + (threadIdx.x >> 6);
    if (w >= N) return;
    int lane = threadIdx.x & 63;
    int o = lane >> 3, c = lane & 7;
    int so = 2 * o;

    int n1 = w + stride, n2 = w + 2 * stride;
    uint_t bd0 = bd[w];
    uint_t bd1 = (n1 < N) ? bd[n1] : 0u;
    uint2 idx0 = *(const uint2*)&csr[MKBEG(w, bd0) + so];

    for (int node = w; node < N; ) {
        uint_t bd2 = (n2 < N) ? bd[n2] : 0u;          // prefetch bd +2
        uint2 idx1 = make_uint2((uint_t)N, (uint_t)N); // prefetch next node window 0
        if (n1 < N) idx1 = *(const uint2*)&csr[MKBEG(n1, bd1) + so];
        int nw = NWIN(bd0);
        int beg0 = MKBEG(node, bd0);
        f32x2 a[4] = {};
        if (o == 0) {
            uint4 u = *(const uint4*)&y[(size_t)node * 32 + c * 4];
            ACCP(u);
        }
        uint2 cur = idx0;
        for (int wd = 1; wd < nw; ++wd) {
            uint2 nxt = *(const uint2*)&csr[beg0 + wd * 16 + so];
            uint4 u0 = *(const uint4*)&y[(size_t)cur.x * 32 + c * 4]; ACCP(u0);
            uint4 u1 = *(const uint4*)&y[(size_t)cur.y * 32 + c * 4]; ACCP(u1);
            cur = nxt;
        }
        {
            uint4 u0 = *(const uint4*)&y[(size_t)cur.x * 32 + c * 4]; ACCP(u0);
            uint4 u1 = *(const uint4*)&y[(size_t)cur.y * 32 + c * 4]; ACCP(u1);
        }
        #pragma unroll
        for (int k = 0; k < 4; ++k) {
            a[k].x += __shfl_xor(a[k].x, 8);  a[k].y += __shfl_xor(a[k].y, 8);
            a[k].x += __shfl_xor(a[k].x, 16); a[k].y += __shfl_xor(a[k].y, 16);
            a[k].x += __shfl_xor(a[k].x, 32); a[k].y += __shfl_xor(a[k].y, 32);
        }
        if (o == 0) {
            float di = dinv[node];
            float4 b0 = *(const float4*)&bias[c * 8];
            float4 b1 = *(const float4*)&bias[c * 8 + 4];
            float o0 = fmaxf(a[0].x * di + b0.x, 0.f);
            float o1 = fmaxf(a[0].y * di + b0.y, 0.f);
            float o2 = fmaxf(a[1].x * di + b0.z, 0.f);
            float o3 = fmaxf(a[1].y * di + b0.w, 0.f);
            float o4 = fmaxf(a[2].x * di + b1.x, 0.f);
            float o5 = fmaxf(a[2].y * di + b1.y, 0.f);
            float o6 = fmaxf(a[3].x * di + b1.z, 0.f);
            float o7 = fmaxf(a[3].y * di + b1.w, 0.f);
            uint4 r = make_uint4(cvtpk(o0, o1), cvtpk(o2, o3), cvtpk(o4, o5), cvtpk(o6, o7));
            *(uint4*)&h[(size_t)node * 32 + c * 4] = r;
        }
        node = n1; n1 = n2; n2 += stride;
        bd0 = bd1; bd1 = bd2; idx0 = idx1;
    }
}

// ---- GEMM2 (MFMA): y2[N,32 uints, cols 0..39] = bf16pack((h @ W2) * dinv[row]) ----
__global__ __launch_bounds__(256) void gemm2_mfma(
    const uint_t* __restrict__ h, const uint_t* __restrict__ Wb,
    const float* __restrict__ dinv, uint_t* __restrict__ y, int N)
{
    __shared__ uint_t ldsW[1536];   // 6 KB
    int t = threadIdx.x;
    {
        const uint4* s4 = (const uint4*)Wb;
        uint4* d4 = (uint4*)ldsW;
        for (int i = t; i < 384; i += 256) d4[i] = s4[i];
    }
    __syncthreads();
    int wid = t >> 6, lane = t & 63;
    int m = lane & 15, kb = lane >> 4;
    int wr = blockIdx.x * 128 + wid * 32;
    int ra0 = min(wr + m, N - 1);
    int ra1 = min(wr + 16 + m, N - 1);
    f32x4 acc[2][3] = {};
    #pragma unroll
    for (int ks = 0; ks < 2; ++ks) {
        uint4 ua = *(const uint4*)&h[(size_t)ra0 * 32 + ks * 16 + kb * 4];
        uint4 ub = *(const uint4*)&h[(size_t)ra1 * 32 + ks * 16 + kb * 4];
        bf16x8 fa0 = u4_to_bf(ua), fa1 = u4_to_bf(ub);
        #pragma unroll
        for (int ct = 0; ct < 3; ++ct) {
            uint4 wu = *(uint4*)&ldsW[((ct * 2 + ks) * 64 + lane) * 4];
            bf16x8 fb = u4_to_bf(wu);
            acc[0][ct] = __builtin_amdgcn_mfma_f32_16x16x32_bf16(fa0, fb, acc[0][ct], 0, 0, 0);
            acc[1][ct] = __builtin_amdgcn_mfma_f32_16x16x32_bf16(fa1, fb, acc[1][ct], 0, 0, 0);
        }
    }
    int rq = lane >> 4;
    #pragma unroll
    for (int rt = 0; rt < 2; ++rt) {
        float dv[4]; int rows[4];
        #pragma unroll
        for (int j = 0; j < 4; ++j) {
            int r = wr + rt * 16 + rq * 4 + j;
            rows[j] = r;
            dv[j] = dinv[min(r, N - 1)];
        }
        #pragma unroll
        for (int ct = 0; ct < 3; ++ct) {
            #pragma unroll
            for (int j = 0; j < 4; ++j) {
                float v = acc[rt][ct][j] * dv[j];
                float pv = __shfl_xor(v, 1);
                bool colok = (ct < 2) || (m < 8);   // col = ct*16+m < 40
                if (!(lane & 1) && colok && rows[j] < N) {
                    y[(size_t)rows[j] * 32 + ct * 8 + (m >> 1)] = cvtpk(v, pv);
                }
            }
        }
    }
}

// ---- agg2: unconditional padded-window gather (5 active uint4 lanes) ----
__global__ __launch_bounds__(256) void agg2_kernel(
    const int* __restrict__ csr, const uint_t* __restrict__ bd,
    const uint_t* __restrict__ y, const float* __restrict__ dinv,
    const float* __restrict__ bias, float* __restrict__ out, int N, int stride)
{
    int w = blockIdx.x * 4 + (threadIdx.x >> 6);
    if (w >= N) return;
    int lane = threadIdx.x & 63;
    int o = lane >> 3, c = lane & 7;
    int so = 2 * o;
    bool act = (c < 5);

    int n1 = w + stride, n2 = w + 2 * stride;
    uint_t bd0 = bd[w];
    uint_t bd1 = (n1 < N) ? bd[n1] : 0u;
    uint2 idx0 = *(const uint2*)&csr[MKBEG(w, bd0) + so];

    for (int node = w; node < N; ) {
        uint_t bd2 = (n2 < N) ? bd[n2] : 0u;
        uint2 idx1 = make_uint2((uint_t)N, (uint_t)N);
        if (n1 < N) idx1 = *(const uint2*)&csr[MKBEG(n1, bd1) + so];
        int nw = NWIN(bd0);
        int beg0 = MKBEG(node, bd0);
        f32x2 a[4] = {};
        if (o == 0 && act) {
            uint4 u = *(const uint4*)&y[(size_t)node * 32 + c * 4];
            ACCP(u);
        }
        uint2 cur = idx0;
        for (int wd = 1; wd < nw; ++wd) {
            uint2 nxt = *(const uint2*)&csr[beg0 + wd * 16 + so];
            if (act) {
                uint4 u0 = *(const uint4*)&y[(size_t)cur.x * 32 + c * 4]; ACCP(u0);
                uint4 u1 = *(const uint4*)&y[(size_t)cur.y * 32 + c * 4]; ACCP(u1);
            }
            cur = nxt;
        }
        if (act) {
            uint4 u0 = *(const uint4*)&y[(size_t)cur.x * 32 + c * 4]; ACCP(u0);
            uint4 u1 = *(const uint4*)&y[(size_t)cur.y * 32 + c * 4]; ACCP(u1);
        }
        #pragma unroll
        for (int k = 0; k < 4; ++k) {
            a[k].x += __shfl_xor(a[k].x, 8);  a[k].y += __shfl_xor(a[k].y, 8);
            a[k].x += __shfl_xor(a[k].x, 16); a[k].y += __shfl_xor(a[k].y, 16);
            a[k].x += __shfl_xor(a[k].x, 32); a[k].y += __shfl_xor(a[k].y, 32);
        }
        if (o == 0 && act) {
            float di = dinv[node];
            float4 b0 = *(const float4*)&bias[c * 8];
            float4 b1 = *(const float4*)&bias[c * 8 + 4];
            float4 r0, r1;
            r0.x = a[0].x * di + b0.x;
            r0.y = a[0].y * di + b0.y;
            r0.z = a[1].x * di + b0.z;
            r0.w = a[1].y * di + b0.w;
            r1.x = a[2].x * di + b1.x;
            r1.y = a[2].y * di + b1.y;
            r1.z = a[3].x * di + b1.z;
            r1.w = a[3].y * di + b1.w;
            *(float4*)&out[(size_t)node * C_OUT + c * 8] = r0;
            *(float4*)&out[(size_t)node * C_OUT + c * 8 + 4] = r1;
        }
        node = n1; n1 = n2; n2 += stride;
        bd0 = bd1; bd1 = bd2; idx0 = idx1;
    }
}

extern "C" void kernel_launch(void* const* d_in, const int* in_sizes, int n_in,
                              void* d_out, int out_size, void* d_ws, size_t ws_size,
                              hipStream_t stream)
{
    const float* x  = (const float*)d_in[0];
    const int*   ei = (const int*)d_in[1];
    const float* W1 = (const float*)d_in[2];
    const float* b1 = (const float*)d_in[3];
    const float* W2 = (const float*)d_in[4];
    const float* b2 = (const float*)d_in[5];
    float* out = (float*)d_out;

    int N = in_sizes[0] / F_IN;
    int E = in_sizes[1] / 2;
    const int* src = ei;
    const int* dst = ei + E;
    int NB = (N + RB - 1) / RB;
    int K = (E + FILL_CHUNK - 1) / FILL_CHUNK;
    int NBLK = (N + 127) / 128;
    int aggStride = AGG_BLOCKS * 4;

    char* ws = (char*)d_ws;
    uint_t* y1b    = (uint_t*)ws;  ws += (size_t)(N + 1) * 32 * 4;  // bf16x2 xW1*dinv (+dummy row)
    uint_t* y2b    = (uint_t*)ws;  ws += (size_t)(N + 1) * 32 * 4;  // bf16x2 hW2*dinv (+dummy row)
    uint_t* h1p    = (uint_t*)ws;  ws += (size_t)N * 32 * 4;        // bf16x2 relu'd h
    float* dinv    = (float*)ws;   ws += (size_t)N * 4;
    uint_t* bd     = (uint_t*)ws;  ws += (size_t)N * 4;             // (excl/16 <<8)|nw
    int*   hist    = (int*)ws;     ws += (size_t)K * (NB + 1) * 4;
    int*   bm      = (int*)ws;     ws += (size_t)K * FILL_CHUNK * 4;
    int*   csr     = (int*)ws;     ws += (size_t)NB * CAP * 4;
    ushort_t* wb1  = (ushort_t*)ws; ws += 8192 * 2;                 // W1 frag-linear bf16
    ushort_t* wb2  = (ushort_t*)ws; ws += 3072 * 2;                 // W2 frag-linear bf16 (48-pad)

    wconv_kernel<<<44, 256, 0, stream>>>(W1, W2, wb1, wb2, y1b, y2b, N);

    bsort_kernel<<<K, FILL_THREADS, 0, stream>>>(src, dst, E, hist, bm, NB);
    csr_gather_kernel<<<NB, 256, 0, stream>>>(hist, bm, K, csr, bd, dinv, N, NB);

    // layer 1
    gemm1_mfma<<<NBLK, 256, 0, stream>>>(x, (const uint_t*)wb1, dinv, y1b, N);
    agg1_kernel<<<AGG_BLOCKS, 256, 0, stream>>>(csr, bd, y1b, dinv, b1, h1p, N, aggStride);

    // layer 2
    gemm2_mfma<<<NBLK, 256, 0, stream>>>(h1p, (const uint_t*)wb2, dinv, y2b, N);
    agg2_kernel<<<AGG_BLOCKS, 256, 0, stream>>>(csr, bd, y2b, dinv, b2, out, N, aggStride);
}